// Round 2
// baseline (228.056 us; speedup 1.0000x reference)
//
#include <hip/hip_runtime.h>

#define BB 128
#define DD 8732
#define OO 16
#define CC 21
#define CH 16       // chunks per image in match phase A
#define CHUNK 546   // ceil(DD/CH)
#define NBLK_D 35   // ceil(DD/256)
#define NV 35       // per-thread register values in topk

struct Accum { float loc_sl1; float conf_pos; float conf_neg; int n_pos; };

__device__ __forceinline__ float smoothl1(float d) {
    float ad = fabsf(d);
    return (ad < 1.0f) ? 0.5f * d * d : ad - 0.5f;
}

// ---------------- Phase A: per-chunk partial argmax_d(iou) for each gt o ----
// key = (iou_bits << 32) | (DD-1-d)  -> u64 max == max iou, tie -> smallest d
__global__ __launch_bounds__(256) void match_a(
    const float4* __restrict__ gt_boxes,   // [B*O] xyxy
    const float4* __restrict__ db,         // [D] cxcywh
    unsigned long long* __restrict__ partial) // [B][O][CH]
{
    const int b = blockIdx.y, ch = blockIdx.x, tid = threadIdx.x;
    __shared__ float s_ax1[OO], s_ay1[OO], s_ax2[OO], s_ay2[OO], s_area[OO];
    __shared__ unsigned long long sred[OO][257];   // padded: avoid group conflicts

    if (tid < OO) {
        float4 g = gt_boxes[b * OO + tid];
        s_ax1[tid] = g.x; s_ay1[tid] = g.y; s_ax2[tid] = g.z; s_ay2[tid] = g.w;
        s_area[tid] = (g.z - g.x) * (g.w - g.y);
    }
    __syncthreads();

    unsigned long long key[OO];
    #pragma unroll
    for (int o = 0; o < OO; ++o) key[o] = 0ull;

    const int d0 = ch * CHUNK;
    const int dend = min(d0 + CHUNK, DD);
    for (int d = d0 + tid; d < dend; d += 256) {
        float4 p = db[d];
        float px1 = p.x - p.z * 0.5f, py1 = p.y - p.w * 0.5f;
        float px2 = p.x + p.z * 0.5f, py2 = p.y + p.w * 0.5f;
        float area_b = (px2 - px1) * (py2 - py1);
        unsigned dl = (unsigned)(DD - 1 - d);
        #pragma unroll
        for (int o = 0; o < OO; ++o) {
            float w = fmaxf(fminf(s_ax2[o], px2) - fmaxf(s_ax1[o], px1), 0.0f);
            float h = fmaxf(fminf(s_ay2[o], py2) - fmaxf(s_ay1[o], py1), 0.0f);
            float inter = w * h;
            float iou = inter / (s_area[o] + area_b - inter);
            unsigned long long kk = ((unsigned long long)__float_as_uint(iou) << 32) | dl;
            if (kk > key[o]) key[o] = kk;
        }
    }
    #pragma unroll
    for (int o = 0; o < OO; ++o) sred[o][tid] = key[o];
    __syncthreads();

    const int g = tid >> 4, j = tid & 15;    // 16 groups x 16 lanes
    unsigned long long mx = sred[g][j];
    #pragma unroll
    for (int t = 1; t < 16; ++t) {
        unsigned long long v = sred[g][j + 16 * t];
        if (v > mx) mx = v;
    }
    #pragma unroll
    for (int off = 8; off; off >>= 1) {
        unsigned long long v = __shfl_xor(mx, off, 16);
        if (v > mx) mx = v;
    }
    if (j == 0) partial[((size_t)b * OO + g) * CH + ch] = mx;
}

// ---------------- Phase B: reduce chunk partials -> best_default_idx --------
__global__ __launch_bounds__(256) void match_b(
    const unsigned long long* __restrict__ partial,
    int* __restrict__ bdi)                 // [B*O]
{
    int i = blockIdx.x * 256 + threadIdx.x;
    if (i >= BB * OO) return;
    unsigned long long mx = 0ull;
    #pragma unroll
    for (int ch = 0; ch < CH; ++ch) {
        unsigned long long v = partial[(size_t)i * CH + ch];
        if (v > mx) mx = v;
    }
    bdi[i] = DD - 1 - (int)(mx & 0xffffffffu);
}

// ---------------- Phase C: fused match-finish + encode + SL1 + CE ----------
__global__ __launch_bounds__(256) void fused_kernel(
    const float4* __restrict__ loc_pred,   // [B*D]
    const float*  __restrict__ cls,        // [B*D*C]
    const float4* __restrict__ gt_boxes,   // [B*O]
    const int*    __restrict__ gt_labels,  // [B*O]
    const float4* __restrict__ db,         // [D]
    const int*    __restrict__ bdi,        // [B*O]
    float* __restrict__ ce_neg,            // [B*D]
    int*   __restrict__ n_positive,        // [B]
    Accum* __restrict__ acc)
{
    const int b = blockIdx.y, jb = blockIdx.x, tid = threadIdx.x;
    const int d = jb * 256 + tid;
    __shared__ float s_cls[256 * CC];      // 21504 B
    __shared__ float s_ax1[OO], s_ay1[OO], s_ax2[OO], s_ay2[OO], s_area[OO];
    __shared__ int   s_lab[OO], s_bdi[OO];
    __shared__ float s_red[12];

    if (tid < OO) {
        float4 g = gt_boxes[b * OO + tid];
        s_ax1[tid] = g.x; s_ay1[tid] = g.y; s_ax2[tid] = g.z; s_ay2[tid] = g.w;
        s_area[tid] = (g.z - g.x) * (g.w - g.y);
        s_lab[tid] = gt_labels[b * OO + tid];
        s_bdi[tid] = bdi[b * OO + tid];
    }
    // stage this block's cls rows (16B aligned: 21504*jb and 733488*b both %16==0)
    const int nrow = min(256, DD - jb * 256);
    const int nvec = nrow * CC / 4;        // always integral here
    const float4* src = (const float4*)(cls + ((size_t)b * DD + (size_t)jb * 256) * CC);
    for (int v = tid; v < nvec; v += 256) ((float4*)s_cls)[v] = src[v];
    __syncthreads();

    float cepos = 0.0f, sl1 = 0.0f; int npos = 0;
    if (d < DD) {
        // recompute per-prior best over the 16 gt (identical arithmetic to A)
        float4 p = db[d];
        float px1 = p.x - p.z * 0.5f, py1 = p.y - p.w * 0.5f;
        float px2 = p.x + p.z * 0.5f, py2 = p.y + p.w * 0.5f;
        float area_b = (px2 - px1) * (py2 - py1);
        float best = -1.0f; int bi = 0;
        #pragma unroll
        for (int o = 0; o < OO; ++o) {
            float w = fmaxf(fminf(s_ax2[o], px2) - fmaxf(s_ax1[o], px1), 0.0f);
            float h = fmaxf(fminf(s_ay2[o], py2) - fmaxf(s_ay1[o], py1), 0.0f);
            float inter = w * h;
            float iou = inter / (s_area[o] + area_b - inter);
            if (iou > best) { best = iou; bi = o; }
        }
        // scatter override, ascending o = last write wins (matches XLA/R1)
        #pragma unroll
        for (int o = 0; o < OO; ++o) {
            if (s_bdi[o] == d) { bi = o; best = 1.0f; }
        }
        int lab = (best < 0.5f) ? 0 : s_lab[bi];

        // CE over 21 classes, row in registers (static indexing)
        float v[CC];
        #pragma unroll
        for (int c = 0; c < CC; ++c) v[c] = s_cls[tid * CC + c];
        float m = v[0];
        #pragma unroll
        for (int c = 1; c < CC; ++c) m = fmaxf(m, v[c]);
        float s = 0.0f;
        #pragma unroll
        for (int c = 0; c < CC; ++c) s += expf(v[c] - m);
        float ce = m + logf(s) - s_cls[tid * CC + lab];  // runtime idx -> LDS read

        size_t gi = (size_t)b * DD + d;
        if (lab > 0) {
            cepos = ce; ce_neg[gi] = 0.0f; npos = 1;
            float ax1 = s_ax1[bi], ay1 = s_ay1[bi], ax2 = s_ax2[bi], ay2 = s_ay2[bi];
            float cx = (ax1 + ax2) * 0.5f, cy = (ay1 + ay2) * 0.5f;
            float w = ax2 - ax1, h = ay2 - ay1;
            float gx = (cx - p.x) / (p.z / 10.0f);
            float gy = (cy - p.y) / (p.w / 10.0f);
            float gw = logf(w / p.z) * 5.0f;
            float gh = logf(h / p.w) * 5.0f;
            float4 lp = loc_pred[gi];
            sl1 = smoothl1(lp.x - gx) + smoothl1(lp.y - gy)
                + smoothl1(lp.z - gw) + smoothl1(lp.w - gh);
        } else {
            ce_neg[gi] = ce;
        }
    }

    // block reduce (wave shfl + 4-entry LDS combine)
    float npf = (float)npos;
    #pragma unroll
    for (int off = 32; off; off >>= 1) {
        cepos += __shfl_xor(cepos, off);
        sl1   += __shfl_xor(sl1, off);
        npf   += __shfl_xor(npf, off);
    }
    const int w = tid >> 6;
    if ((tid & 63) == 0) { s_red[w*3+0] = cepos; s_red[w*3+1] = sl1; s_red[w*3+2] = npf; }
    __syncthreads();
    if (tid == 0) {
        float cp = 0, sv = 0, np = 0;
        #pragma unroll
        for (int q = 0; q < 4; ++q) { cp += s_red[q*3+0]; sv += s_red[q*3+1]; np += s_red[q*3+2]; }
        int npi = (int)np;
        atomicAdd(&acc->conf_pos, cp);
        atomicAdd(&acc->loc_sl1, sv);
        atomicAdd(&acc->n_pos, npi);
        atomicAdd(&n_positive[b], npi);
    }
}

// ---------------- topk: sum of top (3*n_pos) negatives, row in registers ---
__global__ __launch_bounds__(256) void topk_kernel(
    const float* __restrict__ ce_neg,
    const int* __restrict__ n_positive,
    Accum* __restrict__ acc)
{
    const int b = blockIdx.x, tid = threadIdx.x;
    __shared__ int   s_cnt[4];
    __shared__ float s_f[4];

    int k = 3 * n_positive[b];
    if (k <= 0) return;                    // uniform across block
    if (k > DD) k = DD;

    float vals[NV];
    #pragma unroll
    for (int q = 0; q < NV; ++q) {
        int d = q * 256 + tid;
        vals[q] = (d < DD) ? ce_neg[(size_t)b * DD + d] : 0.0f;  // pads: 0 < any mid
    }

    // binary search k-th largest over non-negative float bit patterns
    unsigned lo = 0u, hi = 0x7f800000u;
    while (hi - lo > 1u) {
        unsigned mid = lo + ((hi - lo) >> 1);
        float t = __uint_as_float(mid);
        int c = 0;
        #pragma unroll
        for (int q = 0; q < NV; ++q) c += (vals[q] >= t) ? 1 : 0;
        #pragma unroll
        for (int off = 32; off; off >>= 1) c += __shfl_xor(c, off);
        if ((tid & 63) == 0) s_cnt[tid >> 6] = c;
        __syncthreads();
        int cnt = s_cnt[0] + s_cnt[1] + s_cnt[2] + s_cnt[3];
        __syncthreads();
        if (cnt >= k) lo = mid; else hi = mid;
    }
    float vk = __uint_as_float(lo);

    float ssum = 0.0f; int cgt = 0;
    #pragma unroll
    for (int q = 0; q < NV; ++q) {
        float v = vals[q];
        if (v > vk) { ssum += v; ++cgt; }
    }
    #pragma unroll
    for (int off = 32; off; off >>= 1) { ssum += __shfl_xor(ssum, off); cgt += __shfl_xor(cgt, off); }
    if ((tid & 63) == 0) { s_f[tid >> 6] = ssum; s_cnt[tid >> 6] = cgt; }
    __syncthreads();
    if (tid == 0) {
        float row = s_f[0]+s_f[1]+s_f[2]+s_f[3]
                  + (float)(k - (s_cnt[0]+s_cnt[1]+s_cnt[2]+s_cnt[3])) * vk;
        atomicAdd(&acc->conf_neg, row);
    }
}

__global__ void finalize_kernel(const Accum* __restrict__ acc, float* __restrict__ out) {
    float np = (float)acc->n_pos;
    out[0] = acc->loc_sl1 / (np * 4.0f) + (acc->conf_neg + acc->conf_pos) / np;
}

extern "C" void kernel_launch(void* const* d_in, const int* in_sizes, int n_in,
                              void* d_out, int out_size, void* d_ws, size_t ws_size,
                              hipStream_t stream) {
    (void)in_sizes; (void)n_in; (void)out_size; (void)ws_size;
    const float4* loc_pred  = (const float4*)d_in[0];
    const float*  cls_pred  = (const float*)d_in[1];
    const float4* gt_boxes  = (const float4*)d_in[2];
    const int*    gt_labels = (const int*)d_in[3];
    const float4* db        = (const float4*)d_in[4];

    char* ws = (char*)d_ws;
    unsigned long long* partial = (unsigned long long*)ws;          // B*O*CH u64 = 256 KB
    size_t off = (size_t)BB * OO * CH * sizeof(unsigned long long);
    int* bdi = (int*)(ws + off);                                     // B*O ints
    off += (size_t)BB * OO * sizeof(int);
    float* ce_neg = (float*)(ws + off);                              // B*D floats
    off += (size_t)BB * DD * sizeof(float);
    int* n_positive = (int*)(ws + off);                              // B ints
    size_t zero_off = off;
    off += (size_t)BB * sizeof(int);
    Accum* acc = (Accum*)(ws + off);
    off += sizeof(Accum);

    hipMemsetAsync(ws + zero_off, 0, off - zero_off, stream);

    match_a<<<dim3(CH, BB), 256, 0, stream>>>(gt_boxes, db, partial);
    match_b<<<(BB * OO + 255) / 256, 256, 0, stream>>>(partial, bdi);
    fused_kernel<<<dim3(NBLK_D, BB), 256, 0, stream>>>(loc_pred, cls_pred, gt_boxes,
                                                       gt_labels, db, bdi,
                                                       ce_neg, n_positive, acc);
    topk_kernel<<<BB, 256, 0, stream>>>(ce_neg, n_positive, acc);
    finalize_kernel<<<1, 1, 0, stream>>>(acc, (float*)d_out);
}

// Round 3
// 210.006 us; speedup vs baseline: 1.0859x; 1.0859x over previous
//
#include <hip/hip_runtime.h>

#define BB 128
#define DD 8732
#define OO 16
#define CC 21
#define CH 16       // chunks per image in match phase A
#define CHUNK 546   // ceil(DD/CH)
#define NBLK_D 35   // ceil(DD/256)
#define NG (BB * DD / 4)   // 4-row groups for CE
#define NV 35       // per-thread register values in topk

struct Accum { float loc_sl1; float conf_pos; float conf_neg; int n_pos; };

__device__ __forceinline__ float smoothl1(float d) {
    float ad = fabsf(d);
    return (ad < 1.0f) ? 0.5f * d * d : ad - 0.5f;
}

// ---------------- Phase A: per-chunk partial argmax_d(iou) for each gt o ----
// key = (iou_bits << 32) | (DD-1-d)  -> u64 max == max iou, tie -> smallest d
__global__ __launch_bounds__(256) void match_a(
    const float4* __restrict__ gt_boxes,   // [B*O] xyxy
    const float4* __restrict__ db,         // [D] cxcywh
    unsigned long long* __restrict__ partial) // [B][O][CH]
{
    const int b = blockIdx.y, ch = blockIdx.x, tid = threadIdx.x;
    __shared__ float s_ax1[OO], s_ay1[OO], s_ax2[OO], s_ay2[OO], s_area[OO];
    __shared__ unsigned long long swave[4][OO];

    if (tid < OO) {
        float4 g = gt_boxes[b * OO + tid];
        s_ax1[tid] = g.x; s_ay1[tid] = g.y; s_ax2[tid] = g.z; s_ay2[tid] = g.w;
        s_area[tid] = (g.z - g.x) * (g.w - g.y);
    }
    __syncthreads();

    unsigned long long key[OO];
    #pragma unroll
    for (int o = 0; o < OO; ++o) key[o] = 0ull;

    const int d0 = ch * CHUNK;
    const int dend = min(d0 + CHUNK, DD);
    for (int d = d0 + tid; d < dend; d += 256) {
        float4 p = db[d];
        float px1 = p.x - p.z * 0.5f, py1 = p.y - p.w * 0.5f;
        float px2 = p.x + p.z * 0.5f, py2 = p.y + p.w * 0.5f;
        float area_b = (px2 - px1) * (py2 - py1);
        unsigned dl = (unsigned)(DD - 1 - d);
        #pragma unroll
        for (int o = 0; o < OO; ++o) {
            float w = fmaxf(fminf(s_ax2[o], px2) - fmaxf(s_ax1[o], px1), 0.0f);
            float h = fmaxf(fminf(s_ay2[o], py2) - fmaxf(s_ay1[o], py1), 0.0f);
            float inter = w * h;
            float iou = inter / (s_area[o] + area_b - inter);
            unsigned long long kk = ((unsigned long long)__float_as_uint(iou) << 32) | dl;
            if (kk > key[o]) key[o] = kk;
        }
    }
    #pragma unroll
    for (int o = 0; o < OO; ++o) {
        unsigned long long k = key[o];
        #pragma unroll
        for (int off = 32; off; off >>= 1) {
            unsigned long long v = __shfl_xor(k, off);
            if (v > k) k = v;
        }
        if ((tid & 63) == 0) swave[tid >> 6][o] = k;
    }
    __syncthreads();
    if (tid < OO) {
        unsigned long long m = swave[0][tid];
        #pragma unroll
        for (int w = 1; w < 4; ++w) if (swave[w][tid] > m) m = swave[w][tid];
        partial[((size_t)b * OO + tid) * CH + ch] = m;
    }
}

// ---------------- Phase B: reduce chunk partials -> best_default_idx --------
__global__ __launch_bounds__(256) void match_b(
    const unsigned long long* __restrict__ partial,
    int* __restrict__ bdi)                 // [B*O]
{
    int i = blockIdx.x * 256 + threadIdx.x;
    if (i >= BB * OO) return;
    unsigned long long mx = 0ull;
    #pragma unroll
    for (int ch = 0; ch < CH; ++ch) {
        unsigned long long v = partial[(size_t)i * CH + ch];
        if (v > mx) mx = v;
    }
    bdi[i] = DD - 1 - (int)(mx & 0xffffffffu);
}

// ---------------- labels + encode + SmoothL1 + n_pos (tiny LDS) ------------
__global__ __launch_bounds__(256) void label_kernel(
    const float4* __restrict__ loc_pred,   // [B*D]
    const float4* __restrict__ gt_boxes,   // [B*O]
    const int*    __restrict__ gt_labels,  // [B*O]
    const float4* __restrict__ db,         // [D]
    const int*    __restrict__ bdi,        // [B*O]
    unsigned char* __restrict__ conf_t,    // [B*D]
    int*   __restrict__ n_positive,        // [B]
    Accum* __restrict__ acc)
{
    const int b = blockIdx.y, jb = blockIdx.x, tid = threadIdx.x;
    const int d = jb * 256 + tid;
    __shared__ float s_ax1[OO], s_ay1[OO], s_ax2[OO], s_ay2[OO], s_area[OO];
    __shared__ int   s_lab[OO], s_bdi[OO];
    __shared__ float s_red[12];

    if (tid < OO) {
        float4 g = gt_boxes[b * OO + tid];
        s_ax1[tid] = g.x; s_ay1[tid] = g.y; s_ax2[tid] = g.z; s_ay2[tid] = g.w;
        s_area[tid] = (g.z - g.x) * (g.w - g.y);
        s_lab[tid] = gt_labels[b * OO + tid];
        s_bdi[tid] = bdi[b * OO + tid];
    }
    __syncthreads();

    float sl1 = 0.0f; int npos = 0;
    if (d < DD) {
        float4 p = db[d];
        float px1 = p.x - p.z * 0.5f, py1 = p.y - p.w * 0.5f;
        float px2 = p.x + p.z * 0.5f, py2 = p.y + p.w * 0.5f;
        float area_b = (px2 - px1) * (py2 - py1);
        float best = -1.0f; int bi = 0;
        #pragma unroll
        for (int o = 0; o < OO; ++o) {
            float w = fmaxf(fminf(s_ax2[o], px2) - fmaxf(s_ax1[o], px1), 0.0f);
            float h = fmaxf(fminf(s_ay2[o], py2) - fmaxf(s_ay1[o], py1), 0.0f);
            float inter = w * h;
            float iou = inter / (s_area[o] + area_b - inter);
            if (iou > best) { best = iou; bi = o; }   // first occurrence over o
        }
        // scatter override, ascending o = last write wins (matches XLA)
        #pragma unroll
        for (int o = 0; o < OO; ++o) {
            if (s_bdi[o] == d) { bi = o; best = 1.0f; }
        }
        int lab = (best < 0.5f) ? 0 : s_lab[bi];
        conf_t[(size_t)b * DD + d] = (unsigned char)lab;
        if (lab > 0) {
            npos = 1;
            float ax1 = s_ax1[bi], ay1 = s_ay1[bi], ax2 = s_ax2[bi], ay2 = s_ay2[bi];
            float cx = (ax1 + ax2) * 0.5f, cy = (ay1 + ay2) * 0.5f;
            float w = ax2 - ax1, h = ay2 - ay1;
            float gx = (cx - p.x) / (p.z / 10.0f);
            float gy = (cy - p.y) / (p.w / 10.0f);
            float gw = logf(w / p.z) * 5.0f;
            float gh = logf(h / p.w) * 5.0f;
            float4 lp = loc_pred[(size_t)b * DD + d];
            sl1 = smoothl1(lp.x - gx) + smoothl1(lp.y - gy)
                + smoothl1(lp.z - gw) + smoothl1(lp.w - gh);
        }
    }
    float npf = (float)npos;
    #pragma unroll
    for (int off = 32; off; off >>= 1) {
        sl1 += __shfl_xor(sl1, off);
        npf += __shfl_xor(npf, off);
    }
    const int w = tid >> 6;
    if ((tid & 63) == 0) { s_red[w*2+0] = sl1; s_red[w*2+1] = npf; }
    __syncthreads();
    if (tid == 0) {
        float sv = 0, np = 0;
        #pragma unroll
        for (int q = 0; q < 4; ++q) { sv += s_red[q*2+0]; np += s_red[q*2+1]; }
        int npi = (int)np;
        atomicAdd(&acc->loc_sl1, sv);
        atomicAdd(&acc->n_pos, npi);
        atomicAdd(&n_positive[b], npi);
    }
}

// ---------------- CE: one thread per 4 rows (= 21 aligned float4 loads) ----
__global__ __launch_bounds__(256) void ce4_kernel(
    const float4* __restrict__ cls4,       // [NG*21]
    const unsigned char* __restrict__ conf_t,
    float4* __restrict__ ce_neg4,          // [NG]
    Accum* __restrict__ acc)
{
    const int g = blockIdx.x * 256 + threadIdx.x;
    float cepos = 0.0f;
    if (g < NG) {
        const float4* src = cls4 + (size_t)g * 21;
        float e[84];
        #pragma unroll
        for (int j = 0; j < 21; ++j) {
            float4 q = src[j];                  // 21 independent loads in flight
            e[4*j+0] = q.x; e[4*j+1] = q.y; e[4*j+2] = q.z; e[4*j+3] = q.w;
        }
        uchar4 lb = ((const uchar4*)conf_t)[g];
        int labs[4] = {lb.x, lb.y, lb.z, lb.w};
        float out[4];
        #pragma unroll
        for (int r = 0; r < 4; ++r) {
            float m = e[21*r];
            #pragma unroll
            for (int c = 1; c < CC; ++c) m = fmaxf(m, e[21*r+c]);
            float s = 0.0f;
            #pragma unroll
            for (int c = 0; c < CC; ++c) s += expf(e[21*r+c] - m);
            int lab = labs[r];
            float xl = e[21*r];
            #pragma unroll
            for (int c = 1; c < CC; ++c) xl = (lab == c) ? e[21*r+c] : xl;  // static idx
            float ce = m + logf(s) - xl;
            if (lab > 0) { cepos += ce; out[r] = 0.0f; }
            else out[r] = ce;
        }
        ce_neg4[g] = make_float4(out[0], out[1], out[2], out[3]);
    }
    __shared__ float s_f[4];
    #pragma unroll
    for (int off = 32; off; off >>= 1) cepos += __shfl_xor(cepos, off);
    if ((threadIdx.x & 63) == 0) s_f[threadIdx.x >> 6] = cepos;
    __syncthreads();
    if (threadIdx.x == 0)
        atomicAdd(&acc->conf_pos, s_f[0] + s_f[1] + s_f[2] + s_f[3]);
}

// ---------------- topk: sum of top (3*n_pos) negatives, row in registers ---
__global__ __launch_bounds__(256) void topk_kernel(
    const float* __restrict__ ce_neg,
    const int* __restrict__ n_positive,
    Accum* __restrict__ acc)
{
    const int b = blockIdx.x, tid = threadIdx.x;
    __shared__ int   s_cnt[4];
    __shared__ float s_f[4];

    int k = 3 * n_positive[b];
    if (k <= 0) return;                    // uniform across block
    if (k > DD) k = DD;

    float vals[NV];
    #pragma unroll
    for (int q = 0; q < NV; ++q) {
        int d = q * 256 + tid;
        vals[q] = (d < DD) ? ce_neg[(size_t)b * DD + d] : 0.0f;
    }

    unsigned lo = 0u, hi = 0x7f800000u;
    while (hi - lo > 1u) {
        unsigned mid = lo + ((hi - lo) >> 1);
        float t = __uint_as_float(mid);
        int c = 0;
        #pragma unroll
        for (int q = 0; q < NV; ++q) c += (vals[q] >= t) ? 1 : 0;
        #pragma unroll
        for (int off = 32; off; off >>= 1) c += __shfl_xor(c, off);
        if ((tid & 63) == 0) s_cnt[tid >> 6] = c;
        __syncthreads();
        int cnt = s_cnt[0] + s_cnt[1] + s_cnt[2] + s_cnt[3];
        __syncthreads();
        if (cnt >= k) lo = mid; else hi = mid;
    }
    float vk = __uint_as_float(lo);

    float ssum = 0.0f; int cgt = 0;
    #pragma unroll
    for (int q = 0; q < NV; ++q) {
        float v = vals[q];
        if (v > vk) { ssum += v; ++cgt; }
    }
    #pragma unroll
    for (int off = 32; off; off >>= 1) { ssum += __shfl_xor(ssum, off); cgt += __shfl_xor(cgt, off); }
    if ((tid & 63) == 0) { s_f[tid >> 6] = ssum; s_cnt[tid >> 6] = cgt; }
    __syncthreads();
    if (tid == 0) {
        float row = s_f[0]+s_f[1]+s_f[2]+s_f[3]
                  + (float)(k - (s_cnt[0]+s_cnt[1]+s_cnt[2]+s_cnt[3])) * vk;
        atomicAdd(&acc->conf_neg, row);
    }
}

__global__ void finalize_kernel(const Accum* __restrict__ acc, float* __restrict__ out) {
    float np = (float)acc->n_pos;
    out[0] = acc->loc_sl1 / (np * 4.0f) + (acc->conf_neg + acc->conf_pos) / np;
}

extern "C" void kernel_launch(void* const* d_in, const int* in_sizes, int n_in,
                              void* d_out, int out_size, void* d_ws, size_t ws_size,
                              hipStream_t stream) {
    (void)in_sizes; (void)n_in; (void)out_size; (void)ws_size;
    const float4* loc_pred  = (const float4*)d_in[0];
    const float*  cls_pred  = (const float*)d_in[1];
    const float4* gt_boxes  = (const float4*)d_in[2];
    const int*    gt_labels = (const int*)d_in[3];
    const float4* db        = (const float4*)d_in[4];

    char* ws = (char*)d_ws;
    unsigned long long* partial = (unsigned long long*)ws;          // B*O*CH u64 = 256 KB
    size_t off = (size_t)BB * OO * CH * sizeof(unsigned long long);
    int* bdi = (int*)(ws + off);                                     // B*O ints
    off += (size_t)BB * OO * sizeof(int);
    float* ce_neg = (float*)(ws + off);                              // B*D floats (16B aligned)
    off += (size_t)BB * DD * sizeof(float);
    unsigned char* conf_t = (unsigned char*)(ws + off);              // B*D bytes
    off += ((size_t)BB * DD + 255) & ~(size_t)255;
    int* n_positive = (int*)(ws + off);                              // B ints
    size_t zero_off = off;
    off += (size_t)BB * sizeof(int);
    Accum* acc = (Accum*)(ws + off);
    off += sizeof(Accum);

    hipMemsetAsync(ws + zero_off, 0, off - zero_off, stream);

    match_a<<<dim3(CH, BB), 256, 0, stream>>>(gt_boxes, db, partial);
    match_b<<<(BB * OO + 255) / 256, 256, 0, stream>>>(partial, bdi);
    label_kernel<<<dim3(NBLK_D, BB), 256, 0, stream>>>(loc_pred, gt_boxes, gt_labels,
                                                       db, bdi, conf_t, n_positive, acc);
    ce4_kernel<<<(NG + 255) / 256, 256, 0, stream>>>((const float4*)cls_pred, conf_t,
                                                     (float4*)ce_neg, acc);
    topk_kernel<<<BB, 256, 0, stream>>>(ce_neg, n_positive, acc);
    finalize_kernel<<<1, 1, 0, stream>>>(acc, (float*)d_out);
}

// Round 4
// 112.871 us; speedup vs baseline: 2.0205x; 1.8606x over previous
//
#include <hip/hip_runtime.h>

#define BB 128
#define DD 8732
#define OO 16
#define CC 21
#define CH 16        // chunks per image in match phase A
#define CHUNK 546    // ceil(DD/CH)
#define NBLK_D 35    // ceil(DD/256)
#define NG (BB * DD / 4)          // 4-row groups for CE (= 279424)
#define NCEB ((NG + 255) / 256)   // ce4 blocks (= 1092)
#define NLB (BB * NBLK_D)         // label blocks (= 4480)
#define NV 35        // per-thread register values in topk

__device__ __forceinline__ float smoothl1(float d) {
    float ad = fabsf(d);
    return (ad < 1.0f) ? 0.5f * d * d : ad - 0.5f;
}

// ---------------- Phase A: per-chunk partial argmax_d(iou) for each gt o ----
// key = (iou_bits << 32) | (DD-1-d)  -> u64 max == max iou, tie -> smallest d
__global__ __launch_bounds__(256) void match_a(
    const float4* __restrict__ gt_boxes,   // [B*O] xyxy
    const float4* __restrict__ db,         // [D] cxcywh
    unsigned long long* __restrict__ partial) // [B][O][CH]
{
    const int b = blockIdx.y, ch = blockIdx.x, tid = threadIdx.x;
    __shared__ float s_ax1[OO], s_ay1[OO], s_ax2[OO], s_ay2[OO], s_area[OO];
    __shared__ unsigned long long swave[4][OO];

    if (tid < OO) {
        float4 g = gt_boxes[b * OO + tid];
        s_ax1[tid] = g.x; s_ay1[tid] = g.y; s_ax2[tid] = g.z; s_ay2[tid] = g.w;
        s_area[tid] = (g.z - g.x) * (g.w - g.y);
    }
    __syncthreads();

    unsigned long long key[OO];
    #pragma unroll
    for (int o = 0; o < OO; ++o) key[o] = 0ull;

    const int d0 = ch * CHUNK;
    const int dend = min(d0 + CHUNK, DD);
    for (int d = d0 + tid; d < dend; d += 256) {
        float4 p = db[d];
        float px1 = p.x - p.z * 0.5f, py1 = p.y - p.w * 0.5f;
        float px2 = p.x + p.z * 0.5f, py2 = p.y + p.w * 0.5f;
        float area_b = (px2 - px1) * (py2 - py1);
        unsigned dl = (unsigned)(DD - 1 - d);
        #pragma unroll
        for (int o = 0; o < OO; ++o) {
            float w = fmaxf(fminf(s_ax2[o], px2) - fmaxf(s_ax1[o], px1), 0.0f);
            float h = fmaxf(fminf(s_ay2[o], py2) - fmaxf(s_ay1[o], py1), 0.0f);
            float inter = w * h;
            float iou = inter / (s_area[o] + area_b - inter);
            unsigned long long kk = ((unsigned long long)__float_as_uint(iou) << 32) | dl;
            if (kk > key[o]) key[o] = kk;
        }
    }
    #pragma unroll
    for (int o = 0; o < OO; ++o) {
        unsigned long long k = key[o];
        #pragma unroll
        for (int off = 32; off; off >>= 1) {
            unsigned long long v = __shfl_xor(k, off);
            if (v > k) k = v;
        }
        if ((tid & 63) == 0) swave[tid >> 6][o] = k;
    }
    __syncthreads();
    if (tid < OO) {
        unsigned long long m = swave[0][tid];
        #pragma unroll
        for (int w = 1; w < 4; ++w) if (swave[w][tid] > m) m = swave[w][tid];
        partial[((size_t)b * OO + tid) * CH + ch] = m;
    }
}

// ---------------- Phase B: reduce chunk partials -> best_default_idx --------
__global__ __launch_bounds__(256) void match_b(
    const unsigned long long* __restrict__ partial,
    int* __restrict__ bdi)                 // [B*O]
{
    int i = blockIdx.x * 256 + threadIdx.x;
    if (i >= BB * OO) return;
    unsigned long long mx = 0ull;
    #pragma unroll
    for (int ch = 0; ch < CH; ++ch) {
        unsigned long long v = partial[(size_t)i * CH + ch];
        if (v > mx) mx = v;
    }
    bdi[i] = DD - 1 - (int)(mx & 0xffffffffu);
}

// ------ labels + encode + SmoothL1 + n_pos; per-block partial outputs ------
__global__ __launch_bounds__(256) void label_kernel(
    const float4* __restrict__ loc_pred,   // [B*D]
    const float4* __restrict__ gt_boxes,   // [B*O]
    const int*    __restrict__ gt_labels,  // [B*O]
    const float4* __restrict__ db,         // [D]
    const int*    __restrict__ bdi,        // [B*O]
    unsigned char* __restrict__ conf_t,    // [B*D]
    float* __restrict__ part_sl1,          // [NLB]
    int*   __restrict__ part_np)           // [NLB] (layout [b][jb])
{
    const int b = blockIdx.y, jb = blockIdx.x, tid = threadIdx.x;
    const int d = jb * 256 + tid;
    __shared__ float s_ax1[OO], s_ay1[OO], s_ax2[OO], s_ay2[OO], s_area[OO];
    __shared__ int   s_lab[OO], s_bdi[OO];
    __shared__ float s_f[4];
    __shared__ int   s_i[4];

    if (tid < OO) {
        float4 g = gt_boxes[b * OO + tid];
        s_ax1[tid] = g.x; s_ay1[tid] = g.y; s_ax2[tid] = g.z; s_ay2[tid] = g.w;
        s_area[tid] = (g.z - g.x) * (g.w - g.y);
        s_lab[tid] = gt_labels[b * OO + tid];
        s_bdi[tid] = bdi[b * OO + tid];
    }
    __syncthreads();

    float sl1 = 0.0f; int npos = 0;
    if (d < DD) {
        float4 p = db[d];
        float px1 = p.x - p.z * 0.5f, py1 = p.y - p.w * 0.5f;
        float px2 = p.x + p.z * 0.5f, py2 = p.y + p.w * 0.5f;
        float area_b = (px2 - px1) * (py2 - py1);
        float best = -1.0f; int bi = 0;
        #pragma unroll
        for (int o = 0; o < OO; ++o) {
            float w = fmaxf(fminf(s_ax2[o], px2) - fmaxf(s_ax1[o], px1), 0.0f);
            float h = fmaxf(fminf(s_ay2[o], py2) - fmaxf(s_ay1[o], py1), 0.0f);
            float inter = w * h;
            float iou = inter / (s_area[o] + area_b - inter);
            if (iou > best) { best = iou; bi = o; }   // first occurrence over o
        }
        // scatter override, ascending o = last write wins (matches XLA)
        #pragma unroll
        for (int o = 0; o < OO; ++o) {
            if (s_bdi[o] == d) { bi = o; best = 1.0f; }
        }
        int lab = (best < 0.5f) ? 0 : s_lab[bi];
        conf_t[(size_t)b * DD + d] = (unsigned char)lab;
        if (lab > 0) {
            npos = 1;
            float ax1 = s_ax1[bi], ay1 = s_ay1[bi], ax2 = s_ax2[bi], ay2 = s_ay2[bi];
            float cx = (ax1 + ax2) * 0.5f, cy = (ay1 + ay2) * 0.5f;
            float w = ax2 - ax1, h = ay2 - ay1;
            float gx = (cx - p.x) / (p.z / 10.0f);
            float gy = (cy - p.y) / (p.w / 10.0f);
            float gw = logf(w / p.z) * 5.0f;
            float gh = logf(h / p.w) * 5.0f;
            float4 lp = loc_pred[(size_t)b * DD + d];
            sl1 = smoothl1(lp.x - gx) + smoothl1(lp.y - gy)
                + smoothl1(lp.z - gw) + smoothl1(lp.w - gh);
        }
    }
    #pragma unroll
    for (int off = 32; off; off >>= 1) {
        sl1 += __shfl_xor(sl1, off);
        npos += __shfl_xor(npos, off);
    }
    const int w = tid >> 6;
    if ((tid & 63) == 0) { s_f[w] = sl1; s_i[w] = npos; }
    __syncthreads();
    if (tid == 0) {
        part_sl1[b * NBLK_D + jb] = s_f[0] + s_f[1] + s_f[2] + s_f[3];
        part_np[b * NBLK_D + jb]  = s_i[0] + s_i[1] + s_i[2] + s_i[3];
    }
}

// ---------------- CE: one thread per 4 rows (= 21 aligned float4 loads) ----
__global__ __launch_bounds__(256) void ce4_kernel(
    const float4* __restrict__ cls4,       // [NG*21]
    const unsigned char* __restrict__ conf_t,
    float4* __restrict__ ce_neg4,          // [NG]
    float* __restrict__ part_ce)           // [NCEB]
{
    const int g = blockIdx.x * 256 + threadIdx.x;
    float cepos = 0.0f;
    if (g < NG) {
        const float4* src = cls4 + (size_t)g * 21;
        float e[84];
        #pragma unroll
        for (int j = 0; j < 21; ++j) {
            float4 q = src[j];                  // 21 independent loads in flight
            e[4*j+0] = q.x; e[4*j+1] = q.y; e[4*j+2] = q.z; e[4*j+3] = q.w;
        }
        uchar4 lb = ((const uchar4*)conf_t)[g];
        int labs[4] = {lb.x, lb.y, lb.z, lb.w};
        float out[4];
        #pragma unroll
        for (int r = 0; r < 4; ++r) {
            float m = e[21*r];
            #pragma unroll
            for (int c = 1; c < CC; ++c) m = fmaxf(m, e[21*r+c]);
            float s = 0.0f;
            #pragma unroll
            for (int c = 0; c < CC; ++c) s += expf(e[21*r+c] - m);
            int lab = labs[r];
            float xl = e[21*r];
            #pragma unroll
            for (int c = 1; c < CC; ++c) xl = (lab == c) ? e[21*r+c] : xl;  // static idx
            float ce = m + logf(s) - xl;
            if (lab > 0) { cepos += ce; out[r] = 0.0f; }
            else out[r] = ce;
        }
        ce_neg4[g] = make_float4(out[0], out[1], out[2], out[3]);
    }
    __shared__ float s_f[4];
    #pragma unroll
    for (int off = 32; off; off >>= 1) cepos += __shfl_xor(cepos, off);
    if ((threadIdx.x & 63) == 0) s_f[threadIdx.x >> 6] = cepos;
    __syncthreads();
    if (threadIdx.x == 0)
        part_ce[blockIdx.x] = s_f[0] + s_f[1] + s_f[2] + s_f[3];
}

// ---------------- topk: sum of top (3*n_pos) negatives, row in registers ---
__global__ __launch_bounds__(256) void topk_kernel(
    const float* __restrict__ ce_neg,
    const int* __restrict__ part_np,       // [B][NBLK_D]
    float* __restrict__ conf_neg_part)     // [B]
{
    const int b = blockIdx.x, tid = threadIdx.x;
    __shared__ int   s_cnt[4];
    __shared__ float s_f[4];

    int np = 0;
    #pragma unroll
    for (int jb = 0; jb < NBLK_D; ++jb) np += part_np[b * NBLK_D + jb];  // uniform
    int k = 3 * np;
    if (k <= 0) { if (tid == 0) conf_neg_part[b] = 0.0f; return; }
    if (k > DD) k = DD;

    float vals[NV];
    #pragma unroll
    for (int q = 0; q < NV; ++q) {
        int d = q * 256 + tid;
        vals[q] = (d < DD) ? ce_neg[(size_t)b * DD + d] : 0.0f;
    }

    unsigned lo = 0u, hi = 0x7f800000u;
    while (hi - lo > 1u) {
        unsigned mid = lo + ((hi - lo) >> 1);
        float t = __uint_as_float(mid);
        int c = 0;
        #pragma unroll
        for (int q = 0; q < NV; ++q) c += (vals[q] >= t) ? 1 : 0;
        #pragma unroll
        for (int off = 32; off; off >>= 1) c += __shfl_xor(c, off);
        if ((tid & 63) == 0) s_cnt[tid >> 6] = c;
        __syncthreads();
        int cnt = s_cnt[0] + s_cnt[1] + s_cnt[2] + s_cnt[3];
        __syncthreads();
        if (cnt >= k) lo = mid; else hi = mid;
    }
    float vk = __uint_as_float(lo);

    float ssum = 0.0f; int cgt = 0;
    #pragma unroll
    for (int q = 0; q < NV; ++q) {
        float v = vals[q];
        if (v > vk) { ssum += v; ++cgt; }
    }
    #pragma unroll
    for (int off = 32; off; off >>= 1) { ssum += __shfl_xor(ssum, off); cgt += __shfl_xor(cgt, off); }
    if ((tid & 63) == 0) { s_f[tid >> 6] = ssum; s_cnt[tid >> 6] = cgt; }
    __syncthreads();
    if (tid == 0) {
        conf_neg_part[b] = s_f[0]+s_f[1]+s_f[2]+s_f[3]
                         + (float)(k - (s_cnt[0]+s_cnt[1]+s_cnt[2]+s_cnt[3])) * vk;
    }
}

// ---------------- final: reduce all partials, emit scalar ------------------
__global__ __launch_bounds__(256) void finalize_kernel(
    const float* __restrict__ part_sl1,       // [NLB]
    const int*   __restrict__ part_np,        // [NLB]
    const float* __restrict__ part_ce,        // [NCEB]
    const float* __restrict__ conf_neg_part,  // [B]
    float* __restrict__ out)
{
    const int tid = threadIdx.x;
    float loc = 0.0f; int np = 0;
    for (int i = tid; i < NLB; i += 256) { loc += part_sl1[i]; np += part_np[i]; }
    float cp = 0.0f;
    for (int i = tid; i < NCEB; i += 256) cp += part_ce[i];
    float cn = (tid < BB) ? conf_neg_part[tid] : 0.0f;

    __shared__ float s_f[12];
    #pragma unroll
    for (int off = 32; off; off >>= 1) {
        loc += __shfl_xor(loc, off);
        cp  += __shfl_xor(cp, off);
        cn  += __shfl_xor(cn, off);
        np  += __shfl_xor(np, off);
    }
    __shared__ int s_i[4];
    const int w = tid >> 6;
    if ((tid & 63) == 0) { s_f[w*3+0] = loc; s_f[w*3+1] = cp; s_f[w*3+2] = cn; s_i[w] = np; }
    __syncthreads();
    if (tid == 0) {
        float L = 0, P = 0, N = 0; int T = 0;
        #pragma unroll
        for (int q = 0; q < 4; ++q) { L += s_f[q*3]; P += s_f[q*3+1]; N += s_f[q*3+2]; T += s_i[q]; }
        float npf = (float)T;
        out[0] = L / (npf * 4.0f) + (N + P) / npf;
    }
}

extern "C" void kernel_launch(void* const* d_in, const int* in_sizes, int n_in,
                              void* d_out, int out_size, void* d_ws, size_t ws_size,
                              hipStream_t stream) {
    (void)in_sizes; (void)n_in; (void)out_size; (void)ws_size;
    const float4* loc_pred  = (const float4*)d_in[0];
    const float*  cls_pred  = (const float*)d_in[1];
    const float4* gt_boxes  = (const float4*)d_in[2];
    const int*    gt_labels = (const int*)d_in[3];
    const float4* db        = (const float4*)d_in[4];

    char* ws = (char*)d_ws;
    size_t off = 0;
    auto alloc = [&](size_t bytes) { char* p = ws + off; off = (off + bytes + 15) & ~(size_t)15; return p; };

    unsigned long long* partial = (unsigned long long*)alloc((size_t)BB * OO * CH * 8);
    float* ce_neg        = (float*)alloc((size_t)BB * DD * 4);
    unsigned char* conf_t = (unsigned char*)alloc((size_t)BB * DD);
    int*   bdi           = (int*)alloc((size_t)BB * OO * 4);
    float* part_sl1      = (float*)alloc((size_t)NLB * 4);
    int*   part_np       = (int*)alloc((size_t)NLB * 4);
    float* part_ce       = (float*)alloc((size_t)NCEB * 4);
    float* conf_neg_part = (float*)alloc((size_t)BB * 4);

    match_a<<<dim3(CH, BB), 256, 0, stream>>>(gt_boxes, db, partial);
    match_b<<<(BB * OO + 255) / 256, 256, 0, stream>>>(partial, bdi);
    label_kernel<<<dim3(NBLK_D, BB), 256, 0, stream>>>(loc_pred, gt_boxes, gt_labels,
                                                       db, bdi, conf_t, part_sl1, part_np);
    ce4_kernel<<<NCEB, 256, 0, stream>>>((const float4*)cls_pred, conf_t,
                                         (float4*)ce_neg, part_ce);
    topk_kernel<<<BB, 256, 0, stream>>>(ce_neg, part_np, conf_neg_part);
    finalize_kernel<<<1, 256, 0, stream>>>(part_sl1, part_np, part_ce, conf_neg_part,
                                           (float*)d_out);
}

// Round 5
// 96.538 us; speedup vs baseline: 2.3623x; 1.1692x over previous
//
#include <hip/hip_runtime.h>

#define BB 128
#define DD 8732
#define OO 16
#define CC 21
#define CH 16        // chunks per image in match phase A
#define CHUNK 546    // ceil(DD/CH)
#define NBLK_D 35    // ceil(DD/256)
#define NLB (BB * NBLK_D)         // fused blocks (= 4480)
#define NV 35        // per-thread register values in topk

__device__ __forceinline__ float smoothl1(float d) {
    float ad = fabsf(d);
    return (ad < 1.0f) ? 0.5f * d * d : ad - 0.5f;
}

// ---------------- Phase A: per-chunk partial argmax_d(iou) for each gt o ----
// key = (iou_bits << 32) | (DD-1-d)  -> u64 max == max iou, tie -> smallest d
__global__ __launch_bounds__(256) void match_a(
    const float4* __restrict__ gt_boxes,   // [B*O] xyxy
    const float4* __restrict__ db,         // [D] cxcywh
    unsigned long long* __restrict__ partial) // [B][O][CH]
{
    const int b = blockIdx.y, ch = blockIdx.x, tid = threadIdx.x;
    __shared__ float s_ax1[OO], s_ay1[OO], s_ax2[OO], s_ay2[OO], s_area[OO];
    __shared__ unsigned long long swave[4][OO];

    if (tid < OO) {
        float4 g = gt_boxes[b * OO + tid];
        s_ax1[tid] = g.x; s_ay1[tid] = g.y; s_ax2[tid] = g.z; s_ay2[tid] = g.w;
        s_area[tid] = (g.z - g.x) * (g.w - g.y);
    }
    __syncthreads();

    unsigned long long key[OO];
    #pragma unroll
    for (int o = 0; o < OO; ++o) key[o] = 0ull;

    const int d0 = ch * CHUNK;
    const int dend = min(d0 + CHUNK, DD);
    for (int d = d0 + tid; d < dend; d += 256) {
        float4 p = db[d];
        float px1 = p.x - p.z * 0.5f, py1 = p.y - p.w * 0.5f;
        float px2 = p.x + p.z * 0.5f, py2 = p.y + p.w * 0.5f;
        float area_b = (px2 - px1) * (py2 - py1);
        unsigned dl = (unsigned)(DD - 1 - d);
        #pragma unroll
        for (int o = 0; o < OO; ++o) {
            float w = fmaxf(fminf(s_ax2[o], px2) - fmaxf(s_ax1[o], px1), 0.0f);
            float h = fmaxf(fminf(s_ay2[o], py2) - fmaxf(s_ay1[o], py1), 0.0f);
            float inter = w * h;
            float iou = inter / (s_area[o] + area_b - inter);
            unsigned long long kk = ((unsigned long long)__float_as_uint(iou) << 32) | dl;
            if (kk > key[o]) key[o] = kk;
        }
    }
    #pragma unroll
    for (int o = 0; o < OO; ++o) {
        unsigned long long k = key[o];
        #pragma unroll
        for (int off = 32; off; off >>= 1) {
            unsigned long long v = __shfl_xor(k, off);
            if (v > k) k = v;
        }
        if ((tid & 63) == 0) swave[tid >> 6][o] = k;
    }
    __syncthreads();
    if (tid < OO) {
        unsigned long long m = swave[0][tid];
        #pragma unroll
        for (int w = 1; w < 4; ++w) if (swave[w][tid] > m) m = swave[w][tid];
        partial[((size_t)b * OO + tid) * CH + ch] = m;
    }
}

// ---- fused: bdi-reduce + match + label + encode/SL1 + CE (LDS-staged) -----
__global__ __launch_bounds__(256) void fused_main(
    const float4* __restrict__ loc_pred,   // [B*D]
    const float*  __restrict__ cls,        // [B*D*C]
    const float4* __restrict__ gt_boxes,   // [B*O]
    const int*    __restrict__ gt_labels,  // [B*O]
    const float4* __restrict__ db,         // [D]
    const unsigned long long* __restrict__ partial, // [B][O][CH]
    float* __restrict__ ce_neg,            // [B*D]
    float* __restrict__ part_sl1,          // [NLB] layout [b][jb]
    int*   __restrict__ part_np,           // [NLB]
    float* __restrict__ part_ce)           // [NLB]
{
    const int b = blockIdx.y, jb = blockIdx.x, tid = threadIdx.x;
    const int d = jb * 256 + tid;
    __shared__ float s_cls[256 * CC];      // 21504 B
    __shared__ float s_ax1[OO], s_ay1[OO], s_ax2[OO], s_ay2[OO], s_area[OO];
    __shared__ int   s_lab[OO], s_bdi[OO];
    __shared__ float s_f[8];
    __shared__ int   s_i[4];

    if (tid < OO) {
        float4 g = gt_boxes[b * OO + tid];
        s_ax1[tid] = g.x; s_ay1[tid] = g.y; s_ax2[tid] = g.z; s_ay2[tid] = g.w;
        s_area[tid] = (g.z - g.x) * (g.w - g.y);
        s_lab[tid] = gt_labels[b * OO + tid];
    }

    // in-block match_b: 256 threads load 16x16 chunk partials, reduce per group of 16
    {
        unsigned long long k = partial[(size_t)b * (OO * CH) + tid]; // o=tid>>4, ch=tid&15
        #pragma unroll
        for (int off = 8; off; off >>= 1) {
            unsigned long long v = __shfl_xor(k, off, 16);
            if (v > k) k = v;
        }
        if ((tid & 15) == 0) s_bdi[tid >> 4] = DD - 1 - (int)(k & 0xffffffffu);
    }

    // stage this block's cls rows (coalesced float4; offsets all 16B-aligned)
    const int nrow = min(256, DD - jb * 256);
    const int nvec = nrow * CC / 4;        // integral: nrow*21 % 4 == 0 for 256 and 28
    const float4* src = (const float4*)(cls + ((size_t)b * DD + (size_t)jb * 256) * CC);
    for (int v = tid; v < nvec; v += 256) ((float4*)s_cls)[v] = src[v];
    __syncthreads();

    float sl1 = 0.0f, cepos = 0.0f; int npos = 0;
    if (d < DD) {
        // per-prior best over 16 gt (same arithmetic as match_a)
        float4 p = db[d];
        float px1 = p.x - p.z * 0.5f, py1 = p.y - p.w * 0.5f;
        float px2 = p.x + p.z * 0.5f, py2 = p.y + p.w * 0.5f;
        float area_b = (px2 - px1) * (py2 - py1);
        float best = -1.0f; int bi = 0;
        #pragma unroll
        for (int o = 0; o < OO; ++o) {
            float w = fmaxf(fminf(s_ax2[o], px2) - fmaxf(s_ax1[o], px1), 0.0f);
            float h = fmaxf(fminf(s_ay2[o], py2) - fmaxf(s_ay1[o], py1), 0.0f);
            float inter = w * h;
            float iou = inter / (s_area[o] + area_b - inter);
            if (iou > best) { best = iou; bi = o; }   // first occurrence over o
        }
        // scatter override, ascending o = last write wins (matches XLA)
        #pragma unroll
        for (int o = 0; o < OO; ++o) {
            if (s_bdi[o] == d) { bi = o; best = 1.0f; }
        }
        int lab = (best < 0.5f) ? 0 : s_lab[bi];

        // CE from LDS row (word stride 21, coprime with 32 banks -> conflict-free)
        float v[CC];
        #pragma unroll
        for (int c = 0; c < CC; ++c) v[c] = s_cls[tid * CC + c];
        float m = v[0];
        #pragma unroll
        for (int c = 1; c < CC; ++c) m = fmaxf(m, v[c]);
        float s = 0.0f;
        #pragma unroll
        for (int c = 0; c < CC; ++c) s += expf(v[c] - m);
        float xl = v[0];
        #pragma unroll
        for (int c = 1; c < CC; ++c) xl = (lab == c) ? v[c] : xl;  // static idx select
        float ce = m + logf(s) - xl;

        size_t gi = (size_t)b * DD + d;
        if (lab > 0) {
            npos = 1; cepos = ce;
            ce_neg[gi] = 0.0f;
            float ax1 = s_ax1[bi], ay1 = s_ay1[bi], ax2 = s_ax2[bi], ay2 = s_ay2[bi];
            float cx = (ax1 + ax2) * 0.5f, cy = (ay1 + ay2) * 0.5f;
            float w = ax2 - ax1, h = ay2 - ay1;
            float gx = (cx - p.x) / (p.z / 10.0f);
            float gy = (cy - p.y) / (p.w / 10.0f);
            float gw = logf(w / p.z) * 5.0f;
            float gh = logf(h / p.w) * 5.0f;
            float4 lp = loc_pred[gi];
            sl1 = smoothl1(lp.x - gx) + smoothl1(lp.y - gy)
                + smoothl1(lp.z - gw) + smoothl1(lp.w - gh);
        } else {
            ce_neg[gi] = ce;
        }
    }

    #pragma unroll
    for (int off = 32; off; off >>= 1) {
        sl1   += __shfl_xor(sl1, off);
        cepos += __shfl_xor(cepos, off);
        npos  += __shfl_xor(npos, off);
    }
    const int w = tid >> 6;
    if ((tid & 63) == 0) { s_f[w*2+0] = sl1; s_f[w*2+1] = cepos; s_i[w] = npos; }
    __syncthreads();
    if (tid == 0) {
        float sv = 0, cp = 0; int np = 0;
        #pragma unroll
        for (int q = 0; q < 4; ++q) { sv += s_f[q*2+0]; cp += s_f[q*2+1]; np += s_i[q]; }
        const int pi = b * NBLK_D + jb;
        part_sl1[pi] = sv;
        part_ce[pi]  = cp;
        part_np[pi]  = np;
    }
}

// ---------------- topk: sum of top (3*n_pos) negatives, row in registers ---
__global__ __launch_bounds__(256) void topk_kernel(
    const float* __restrict__ ce_neg,
    const int* __restrict__ part_np,       // [B][NBLK_D]
    float* __restrict__ conf_neg_part)     // [B]
{
    const int b = blockIdx.x, tid = threadIdx.x;
    __shared__ int   s_cnt[4];
    __shared__ float s_f[4];

    int np = 0;
    #pragma unroll
    for (int jb = 0; jb < NBLK_D; ++jb) np += part_np[b * NBLK_D + jb];  // uniform
    int k = 3 * np;
    if (k <= 0) { if (tid == 0) conf_neg_part[b] = 0.0f; return; }
    if (k > DD) k = DD;

    float vals[NV];
    #pragma unroll
    for (int q = 0; q < NV; ++q) {
        int d = q * 256 + tid;
        vals[q] = (d < DD) ? ce_neg[(size_t)b * DD + d] : 0.0f;
    }

    unsigned lo = 0u, hi = 0x7f800000u;
    while (hi - lo > 1u) {
        unsigned mid = lo + ((hi - lo) >> 1);
        float t = __uint_as_float(mid);
        int c = 0;
        #pragma unroll
        for (int q = 0; q < NV; ++q) c += (vals[q] >= t) ? 1 : 0;
        #pragma unroll
        for (int off = 32; off; off >>= 1) c += __shfl_xor(c, off);
        if ((tid & 63) == 0) s_cnt[tid >> 6] = c;
        __syncthreads();
        int cnt = s_cnt[0] + s_cnt[1] + s_cnt[2] + s_cnt[3];
        __syncthreads();
        if (cnt >= k) lo = mid; else hi = mid;
    }
    float vk = __uint_as_float(lo);

    float ssum = 0.0f; int cgt = 0;
    #pragma unroll
    for (int q = 0; q < NV; ++q) {
        float v = vals[q];
        if (v > vk) { ssum += v; ++cgt; }
    }
    #pragma unroll
    for (int off = 32; off; off >>= 1) { ssum += __shfl_xor(ssum, off); cgt += __shfl_xor(cgt, off); }
    if ((tid & 63) == 0) { s_f[tid >> 6] = ssum; s_cnt[tid >> 6] = cgt; }
    __syncthreads();
    if (tid == 0) {
        conf_neg_part[b] = s_f[0]+s_f[1]+s_f[2]+s_f[3]
                         + (float)(k - (s_cnt[0]+s_cnt[1]+s_cnt[2]+s_cnt[3])) * vk;
    }
}

// ---------------- final: reduce all partials, emit scalar ------------------
__global__ __launch_bounds__(256) void finalize_kernel(
    const float* __restrict__ part_sl1,       // [NLB]
    const int*   __restrict__ part_np,        // [NLB]
    const float* __restrict__ part_ce,        // [NLB]
    const float* __restrict__ conf_neg_part,  // [B]
    float* __restrict__ out)
{
    const int tid = threadIdx.x;
    float loc = 0.0f, cp = 0.0f; int np = 0;
    for (int i = tid; i < NLB; i += 256) {
        loc += part_sl1[i]; cp += part_ce[i]; np += part_np[i];
    }
    float cn = (tid < BB) ? conf_neg_part[tid] : 0.0f;

    __shared__ float s_f[12];
    __shared__ int s_i[4];
    #pragma unroll
    for (int off = 32; off; off >>= 1) {
        loc += __shfl_xor(loc, off);
        cp  += __shfl_xor(cp, off);
        cn  += __shfl_xor(cn, off);
        np  += __shfl_xor(np, off);
    }
    const int w = tid >> 6;
    if ((tid & 63) == 0) { s_f[w*3+0] = loc; s_f[w*3+1] = cp; s_f[w*3+2] = cn; s_i[w] = np; }
    __syncthreads();
    if (tid == 0) {
        float L = 0, P = 0, N = 0; int T = 0;
        #pragma unroll
        for (int q = 0; q < 4; ++q) { L += s_f[q*3]; P += s_f[q*3+1]; N += s_f[q*3+2]; T += s_i[q]; }
        float npf = (float)T;
        out[0] = L / (npf * 4.0f) + (N + P) / npf;
    }
}

extern "C" void kernel_launch(void* const* d_in, const int* in_sizes, int n_in,
                              void* d_out, int out_size, void* d_ws, size_t ws_size,
                              hipStream_t stream) {
    (void)in_sizes; (void)n_in; (void)out_size; (void)ws_size;
    const float4* loc_pred  = (const float4*)d_in[0];
    const float*  cls_pred  = (const float*)d_in[1];
    const float4* gt_boxes  = (const float4*)d_in[2];
    const int*    gt_labels = (const int*)d_in[3];
    const float4* db        = (const float4*)d_in[4];

    char* ws = (char*)d_ws;
    size_t off = 0;
    auto alloc = [&](size_t bytes) { char* p = ws + off; off = (off + bytes + 15) & ~(size_t)15; return p; };

    unsigned long long* partial = (unsigned long long*)alloc((size_t)BB * OO * CH * 8);
    float* ce_neg        = (float*)alloc((size_t)BB * DD * 4);
    float* part_sl1      = (float*)alloc((size_t)NLB * 4);
    int*   part_np       = (int*)alloc((size_t)NLB * 4);
    float* part_ce       = (float*)alloc((size_t)NLB * 4);
    float* conf_neg_part = (float*)alloc((size_t)BB * 4);

    match_a<<<dim3(CH, BB), 256, 0, stream>>>(gt_boxes, db, partial);
    fused_main<<<dim3(NBLK_D, BB), 256, 0, stream>>>(loc_pred, cls_pred, gt_boxes,
                                                     gt_labels, db, partial,
                                                     ce_neg, part_sl1, part_np, part_ce);
    topk_kernel<<<BB, 256, 0, stream>>>(ce_neg, part_np, conf_neg_part);
    finalize_kernel<<<1, 256, 0, stream>>>(part_sl1, part_np, part_ce, conf_neg_part,
                                           (float*)d_out);
}

// Round 6
// 80.643 us; speedup vs baseline: 2.8280x; 1.1971x over previous
//
#include <hip/hip_runtime.h>

#define BB 128
#define DD 8732
#define OO 16
#define CC 21
#define CH 16        // chunks per image in match phase A
#define CHUNK 546    // ceil(DD/CH)
#define NBLK_D 35    // ceil(DD/256)
#define NLB (BB * NBLK_D)         // fused blocks (= 4480)
#define NV 35        // per-thread register values in topk

__device__ __forceinline__ float smoothl1(float d) {
    float ad = fabsf(d);
    return (ad < 1.0f) ? 0.5f * d * d : ad - 0.5f;
}

// ---------------- Phase A: per-chunk partial argmax_d(iou) for each gt o ----
// key = (iou_bits << 32) | (DD-1-d)  -> u64 max == max iou, tie -> smallest d
__global__ __launch_bounds__(256) void match_a(
    const float4* __restrict__ gt_boxes,   // [B*O] xyxy
    const float4* __restrict__ db,         // [D] cxcywh
    unsigned long long* __restrict__ partial) // [B][O][CH]
{
    const int b = blockIdx.y, ch = blockIdx.x, tid = threadIdx.x;
    __shared__ float s_ax1[OO], s_ay1[OO], s_ax2[OO], s_ay2[OO], s_area[OO];
    __shared__ unsigned long long s_keys[OO][257];   // padded stride

    if (tid < OO) {
        float4 g = gt_boxes[b * OO + tid];
        s_ax1[tid] = g.x; s_ay1[tid] = g.y; s_ax2[tid] = g.z; s_ay2[tid] = g.w;
        s_area[tid] = (g.z - g.x) * (g.w - g.y);
    }
    __syncthreads();

    unsigned long long key[OO];
    #pragma unroll
    for (int o = 0; o < OO; ++o) key[o] = 0ull;

    const int d0 = ch * CHUNK;
    const int dend = min(d0 + CHUNK, DD);
    for (int d = d0 + tid; d < dend; d += 256) {
        float4 p = db[d];
        float px1 = p.x - p.z * 0.5f, py1 = p.y - p.w * 0.5f;
        float px2 = p.x + p.z * 0.5f, py2 = p.y + p.w * 0.5f;
        float area_b = (px2 - px1) * (py2 - py1);
        unsigned dl = (unsigned)(DD - 1 - d);
        #pragma unroll
        for (int o = 0; o < OO; ++o) {
            float w = fmaxf(fminf(s_ax2[o], px2) - fmaxf(s_ax1[o], px1), 0.0f);
            float h = fmaxf(fminf(s_ay2[o], py2) - fmaxf(s_ay1[o], py1), 0.0f);
            float inter = w * h;
            float iou = inter / (s_area[o] + area_b - inter);
            unsigned long long kk = ((unsigned long long)__float_as_uint(iou) << 32) | dl;
            if (kk > key[o]) key[o] = kk;
        }
    }
    #pragma unroll
    for (int o = 0; o < OO; ++o) s_keys[o][tid] = key[o];
    __syncthreads();

    // transpose reduce: thread t -> o = t>>4, j = t&15; 16 strided reads + shfl
    const int o = tid >> 4, j = tid & 15;
    unsigned long long mx = s_keys[o][j];
    #pragma unroll
    for (int m = 1; m < 16; ++m) {
        unsigned long long v = s_keys[o][j + 16 * m];
        if (v > mx) mx = v;
    }
    #pragma unroll
    for (int off = 8; off; off >>= 1) {
        unsigned long long v = __shfl_xor(mx, off, 16);
        if (v > mx) mx = v;
    }
    if (j == 0) partial[((size_t)b * OO + o) * CH + ch] = mx;
}

// ---- fused: bdi-reduce + match + label + encode/SL1 + CE (LDS-staged) -----
__global__ __launch_bounds__(256) void fused_main(
    const float4* __restrict__ loc_pred,   // [B*D]
    const float*  __restrict__ cls,        // [B*D*C]
    const float4* __restrict__ gt_boxes,   // [B*O]
    const int*    __restrict__ gt_labels,  // [B*O]
    const float4* __restrict__ db,         // [D]
    const unsigned long long* __restrict__ partial, // [B][O][CH]
    float* __restrict__ ce_neg,            // [B*D]
    float* __restrict__ part_sl1,          // [NLB] layout [b][jb]
    int*   __restrict__ part_np,           // [NLB]
    float* __restrict__ part_ce)           // [NLB]
{
    const int b = blockIdx.y, jb = blockIdx.x, tid = threadIdx.x;
    const int d = jb * 256 + tid;
    __shared__ float s_cls[256 * CC];      // 21504 B
    __shared__ float s_ax1[OO], s_ay1[OO], s_ax2[OO], s_ay2[OO], s_area[OO];
    __shared__ int   s_lab[OO], s_bdi[OO];
    __shared__ float s_f[8];
    __shared__ int   s_i[4];

    if (tid < OO) {
        float4 g = gt_boxes[b * OO + tid];
        s_ax1[tid] = g.x; s_ay1[tid] = g.y; s_ax2[tid] = g.z; s_ay2[tid] = g.w;
        s_area[tid] = (g.z - g.x) * (g.w - g.y);
        s_lab[tid] = gt_labels[b * OO + tid];
    }

    // in-block match_b: 256 threads load 16x16 chunk partials, reduce per group of 16
    {
        unsigned long long k = partial[(size_t)b * (OO * CH) + tid]; // o=tid>>4, ch=tid&15
        #pragma unroll
        for (int off = 8; off; off >>= 1) {
            unsigned long long v = __shfl_xor(k, off, 16);
            if (v > k) k = v;
        }
        if ((tid & 15) == 0) s_bdi[tid >> 4] = DD - 1 - (int)(k & 0xffffffffu);
    }

    // stage this block's cls rows (coalesced float4; offsets all 16B-aligned)
    const int nrow = min(256, DD - jb * 256);
    const int nvec = nrow * CC / 4;        // integral: nrow*21 % 4 == 0 for 256 and 28
    const float4* src = (const float4*)(cls + ((size_t)b * DD + (size_t)jb * 256) * CC);
    for (int v = tid; v < nvec; v += 256) ((float4*)s_cls)[v] = src[v];
    __syncthreads();

    float sl1 = 0.0f, cepos = 0.0f; int npos = 0;
    if (d < DD) {
        // per-prior best over 16 gt (same arithmetic as match_a)
        float4 p = db[d];
        float px1 = p.x - p.z * 0.5f, py1 = p.y - p.w * 0.5f;
        float px2 = p.x + p.z * 0.5f, py2 = p.y + p.w * 0.5f;
        float area_b = (px2 - px1) * (py2 - py1);
        float best = -1.0f; int bi = 0;
        #pragma unroll
        for (int o = 0; o < OO; ++o) {
            float w = fmaxf(fminf(s_ax2[o], px2) - fmaxf(s_ax1[o], px1), 0.0f);
            float h = fmaxf(fminf(s_ay2[o], py2) - fmaxf(s_ay1[o], py1), 0.0f);
            float inter = w * h;
            float iou = inter / (s_area[o] + area_b - inter);
            if (iou > best) { best = iou; bi = o; }   // first occurrence over o
        }
        // scatter override, ascending o = last write wins (matches XLA)
        #pragma unroll
        for (int o = 0; o < OO; ++o) {
            if (s_bdi[o] == d) { bi = o; best = 1.0f; }
        }
        int lab = (best < 0.5f) ? 0 : s_lab[bi];

        // CE from LDS row (word stride 21, coprime with 32 banks -> conflict-free)
        float v[CC];
        #pragma unroll
        for (int c = 0; c < CC; ++c) v[c] = s_cls[tid * CC + c];
        float m = v[0];
        #pragma unroll
        for (int c = 1; c < CC; ++c) m = fmaxf(m, v[c]);
        float s = 0.0f;
        #pragma unroll
        for (int c = 0; c < CC; ++c) s += __expf(v[c] - m);   // v_exp_f32
        float xl = v[0];
        #pragma unroll
        for (int c = 1; c < CC; ++c) xl = (lab == c) ? v[c] : xl;  // static idx select
        float ce = m + __logf(s) - xl;                        // v_log_f32

        size_t gi = (size_t)b * DD + d;
        if (lab > 0) {
            npos = 1; cepos = ce;
            ce_neg[gi] = 0.0f;
            float ax1 = s_ax1[bi], ay1 = s_ay1[bi], ax2 = s_ax2[bi], ay2 = s_ay2[bi];
            float cx = (ax1 + ax2) * 0.5f, cy = (ay1 + ay2) * 0.5f;
            float w = ax2 - ax1, h = ay2 - ay1;
            float gx = (cx - p.x) / (p.z / 10.0f);
            float gy = (cy - p.y) / (p.w / 10.0f);
            float gw = __logf(w / p.z) * 5.0f;
            float gh = __logf(h / p.w) * 5.0f;
            float4 lp = loc_pred[gi];
            sl1 = smoothl1(lp.x - gx) + smoothl1(lp.y - gy)
                + smoothl1(lp.z - gw) + smoothl1(lp.w - gh);
        } else {
            ce_neg[gi] = ce;
        }
    }

    #pragma unroll
    for (int off = 32; off; off >>= 1) {
        sl1   += __shfl_xor(sl1, off);
        cepos += __shfl_xor(cepos, off);
        npos  += __shfl_xor(npos, off);
    }
    const int w = tid >> 6;
    if ((tid & 63) == 0) { s_f[w*2+0] = sl1; s_f[w*2+1] = cepos; s_i[w] = npos; }
    __syncthreads();
    if (tid == 0) {
        float sv = 0, cp = 0; int np = 0;
        #pragma unroll
        for (int q = 0; q < 4; ++q) { sv += s_f[q*2+0]; cp += s_f[q*2+1]; np += s_i[q]; }
        const int pi = b * NBLK_D + jb;
        part_sl1[pi] = sv;
        part_ce[pi]  = cp;
        part_np[pi]  = np;
    }
}

// ---------------- topk: sum of top (3*n_pos) negatives, row in registers ---
__global__ __launch_bounds__(256) void topk_kernel(
    const float* __restrict__ ce_neg,
    const int* __restrict__ part_np,       // [B][NBLK_D]
    float* __restrict__ conf_neg_part)     // [B]
{
    const int b = blockIdx.x, tid = threadIdx.x;
    __shared__ int   s_cnt[4];
    __shared__ float s_f[4];

    int np = 0;
    #pragma unroll
    for (int jb = 0; jb < NBLK_D; ++jb) np += part_np[b * NBLK_D + jb];  // uniform
    int k = 3 * np;
    if (k <= 0) { if (tid == 0) conf_neg_part[b] = 0.0f; return; }
    if (k > DD) k = DD;

    float vals[NV];
    #pragma unroll
    for (int q = 0; q < NV; ++q) {
        int d = q * 256 + tid;
        vals[q] = (d < DD) ? ce_neg[(size_t)b * DD + d] : 0.0f;
    }

    unsigned lo = 0u, hi = 0x7f800000u;
    while (hi - lo > 1u) {
        unsigned mid = lo + ((hi - lo) >> 1);
        float t = __uint_as_float(mid);
        int c = 0;
        #pragma unroll
        for (int q = 0; q < NV; ++q) c += (vals[q] >= t) ? 1 : 0;
        #pragma unroll
        for (int off = 32; off; off >>= 1) c += __shfl_xor(c, off);
        if ((tid & 63) == 0) s_cnt[tid >> 6] = c;
        __syncthreads();
        int cnt = s_cnt[0] + s_cnt[1] + s_cnt[2] + s_cnt[3];
        __syncthreads();
        if (cnt >= k) lo = mid; else hi = mid;
    }
    float vk = __uint_as_float(lo);

    float ssum = 0.0f; int cgt = 0;
    #pragma unroll
    for (int q = 0; q < NV; ++q) {
        float v = vals[q];
        if (v > vk) { ssum += v; ++cgt; }
    }
    #pragma unroll
    for (int off = 32; off; off >>= 1) { ssum += __shfl_xor(ssum, off); cgt += __shfl_xor(cgt, off); }
    if ((tid & 63) == 0) { s_f[tid >> 6] = ssum; s_cnt[tid >> 6] = cgt; }
    __syncthreads();
    if (tid == 0) {
        conf_neg_part[b] = s_f[0]+s_f[1]+s_f[2]+s_f[3]
                         + (float)(k - (s_cnt[0]+s_cnt[1]+s_cnt[2]+s_cnt[3])) * vk;
    }
}

// ---------------- final: reduce all partials, emit scalar ------------------
__global__ __launch_bounds__(256) void finalize_kernel(
    const float* __restrict__ part_sl1,       // [NLB]
    const int*   __restrict__ part_np,        // [NLB]
    const float* __restrict__ part_ce,        // [NLB]
    const float* __restrict__ conf_neg_part,  // [B]
    float* __restrict__ out)
{
    const int tid = threadIdx.x;
    float loc = 0.0f, cp = 0.0f; int np = 0;
    for (int i = tid; i < NLB; i += 256) {
        loc += part_sl1[i]; cp += part_ce[i]; np += part_np[i];
    }
    float cn = (tid < BB) ? conf_neg_part[tid] : 0.0f;

    __shared__ float s_f[12];
    __shared__ int s_i[4];
    #pragma unroll
    for (int off = 32; off; off >>= 1) {
        loc += __shfl_xor(loc, off);
        cp  += __shfl_xor(cp, off);
        cn  += __shfl_xor(cn, off);
        np  += __shfl_xor(np, off);
    }
    const int w = tid >> 6;
    if ((tid & 63) == 0) { s_f[w*3+0] = loc; s_f[w*3+1] = cp; s_f[w*3+2] = cn; s_i[w] = np; }
    __syncthreads();
    if (tid == 0) {
        float L = 0, P = 0, N = 0; int T = 0;
        #pragma unroll
        for (int q = 0; q < 4; ++q) { L += s_f[q*3]; P += s_f[q*3+1]; N += s_f[q*3+2]; T += s_i[q]; }
        float npf = (float)T;
        out[0] = L / (npf * 4.0f) + (N + P) / npf;
    }
}

extern "C" void kernel_launch(void* const* d_in, const int* in_sizes, int n_in,
                              void* d_out, int out_size, void* d_ws, size_t ws_size,
                              hipStream_t stream) {
    (void)in_sizes; (void)n_in; (void)out_size; (void)ws_size;
    const float4* loc_pred  = (const float4*)d_in[0];
    const float*  cls_pred  = (const float*)d_in[1];
    const float4* gt_boxes  = (const float4*)d_in[2];
    const int*    gt_labels = (const int*)d_in[3];
    const float4* db        = (const float4*)d_in[4];

    char* ws = (char*)d_ws;
    size_t off = 0;
    auto alloc = [&](size_t bytes) { char* p = ws + off; off = (off + bytes + 15) & ~(size_t)15; return p; };

    unsigned long long* partial = (unsigned long long*)alloc((size_t)BB * OO * CH * 8);
    float* ce_neg        = (float*)alloc((size_t)BB * DD * 4);
    float* part_sl1      = (float*)alloc((size_t)NLB * 4);
    int*   part_np       = (int*)alloc((size_t)NLB * 4);
    float* part_ce       = (float*)alloc((size_t)NLB * 4);
    float* conf_neg_part = (float*)alloc((size_t)BB * 4);

    match_a<<<dim3(CH, BB), 256, 0, stream>>>(gt_boxes, db, partial);
    fused_main<<<dim3(NBLK_D, BB), 256, 0, stream>>>(loc_pred, cls_pred, gt_boxes,
                                                     gt_labels, db, partial,
                                                     ce_neg, part_sl1, part_np, part_ce);
    topk_kernel<<<BB, 256, 0, stream>>>(ce_neg, part_np, conf_neg_part);
    finalize_kernel<<<1, 256, 0, stream>>>(part_sl1, part_np, part_ce, conf_neg_part,
                                           (float*)d_out);
}

// Round 7
// 75.663 us; speedup vs baseline: 3.0141x; 1.0658x over previous
//
#include <hip/hip_runtime.h>

#define BB 128
#define DD 8732
#define OO 16
#define CC 21
#define CH 16        // chunks per image in match phase A
#define CHUNK 546    // ceil(DD/CH)
#define NBLK_D 35    // ceil(DD/256)
#define NLB (BB * NBLK_D)         // fused blocks (= 4480)
#define NV 35        // per-thread register values in topk

__device__ __forceinline__ float smoothl1(float d) {
    float ad = fabsf(d);
    return (ad < 1.0f) ? 0.5f * d * d : ad - 0.5f;
}

// ---- Phase A: per-chunk argmax_d(iou) per gt o  +  per-d best over o ------
// key = (iou_bits << 32) | (DD-1-d)  -> u64 max == max iou, tie -> smallest d
__global__ __launch_bounds__(256) void match_a(
    const float4* __restrict__ gt_boxes,   // [B*O] xyxy
    const float4* __restrict__ db,         // [D] cxcywh
    unsigned long long* __restrict__ partial, // [B][O][CH]
    float* __restrict__ bovl,              // [B*D] best-over-o iou
    unsigned char* __restrict__ bidx)      // [B*D] argmax-over-o (first occurrence)
{
    const int b = blockIdx.y, ch = blockIdx.x, tid = threadIdx.x;
    __shared__ float s_ax1[OO], s_ay1[OO], s_ax2[OO], s_ay2[OO], s_area[OO];
    __shared__ unsigned long long s_keys[OO][257];   // padded stride

    if (tid < OO) {
        float4 g = gt_boxes[b * OO + tid];
        s_ax1[tid] = g.x; s_ay1[tid] = g.y; s_ax2[tid] = g.z; s_ay2[tid] = g.w;
        s_area[tid] = (g.z - g.x) * (g.w - g.y);
    }
    __syncthreads();

    unsigned long long key[OO];
    #pragma unroll
    for (int o = 0; o < OO; ++o) key[o] = 0ull;

    const int d0 = ch * CHUNK;
    const int dend = min(d0 + CHUNK, DD);
    for (int d = d0 + tid; d < dend; d += 256) {
        float4 p = db[d];
        float px1 = p.x - p.z * 0.5f, py1 = p.y - p.w * 0.5f;
        float px2 = p.x + p.z * 0.5f, py2 = p.y + p.w * 0.5f;
        float area_b = (px2 - px1) * (py2 - py1);
        unsigned dl = (unsigned)(DD - 1 - d);
        float best = -1.0f; int bi = 0;
        #pragma unroll
        for (int o = 0; o < OO; ++o) {
            float w = fmaxf(fminf(s_ax2[o], px2) - fmaxf(s_ax1[o], px1), 0.0f);
            float h = fmaxf(fminf(s_ay2[o], py2) - fmaxf(s_ay1[o], py1), 0.0f);
            float inter = w * h;
            float iou = inter / (s_area[o] + area_b - inter);
            unsigned long long kk = ((unsigned long long)__float_as_uint(iou) << 32) | dl;
            if (kk > key[o]) key[o] = kk;
            if (iou > best) { best = iou; bi = o; }   // first occurrence over o
        }
        bovl[(size_t)b * DD + d] = best;
        bidx[(size_t)b * DD + d] = (unsigned char)bi;
    }
    #pragma unroll
    for (int o = 0; o < OO; ++o) s_keys[o][tid] = key[o];
    __syncthreads();

    // transpose reduce: thread t -> o = t>>4, j = t&15; 16 strided reads + shfl
    const int o = tid >> 4, j = tid & 15;
    unsigned long long mx = s_keys[o][j];
    #pragma unroll
    for (int m = 1; m < 16; ++m) {
        unsigned long long v = s_keys[o][j + 16 * m];
        if (v > mx) mx = v;
    }
    #pragma unroll
    for (int off = 8; off; off >>= 1) {
        unsigned long long v = __shfl_xor(mx, off, 16);
        if (v > mx) mx = v;
    }
    if (j == 0) partial[((size_t)b * OO + o) * CH + ch] = mx;
}

// ---- fused: bdi-reduce + label + encode/SL1 + CE (LDS-staged cls) ---------
__global__ __launch_bounds__(256) void fused_main(
    const float4* __restrict__ loc_pred,   // [B*D]
    const float*  __restrict__ cls,        // [B*D*C]
    const float4* __restrict__ gt_boxes,   // [B*O]
    const int*    __restrict__ gt_labels,  // [B*O]
    const float4* __restrict__ db,         // [D]
    const unsigned long long* __restrict__ partial, // [B][O][CH]
    const float* __restrict__ bovl,        // [B*D]
    const unsigned char* __restrict__ bidx,// [B*D]
    float* __restrict__ ce_neg,            // [B*D]
    float* __restrict__ part_sl1,          // [NLB] layout [b][jb]
    int*   __restrict__ part_np,           // [NLB]
    float* __restrict__ part_ce)           // [NLB]
{
    const int b = blockIdx.y, jb = blockIdx.x, tid = threadIdx.x;
    const int d = jb * 256 + tid;
    __shared__ float s_cls[256 * CC];      // 21504 B
    __shared__ float s_ax1[OO], s_ay1[OO], s_ax2[OO], s_ay2[OO];
    __shared__ int   s_lab[OO], s_bdi[OO];
    __shared__ float s_f[8];
    __shared__ int   s_i[4];

    if (tid < OO) {
        float4 g = gt_boxes[b * OO + tid];
        s_ax1[tid] = g.x; s_ay1[tid] = g.y; s_ax2[tid] = g.z; s_ay2[tid] = g.w;
        s_lab[tid] = gt_labels[b * OO + tid];
    }

    // in-block match_b: 256 threads load 16x16 chunk partials, reduce per group of 16
    {
        unsigned long long k = partial[(size_t)b * (OO * CH) + tid]; // o=tid>>4, ch=tid&15
        #pragma unroll
        for (int off = 8; off; off >>= 1) {
            unsigned long long v = __shfl_xor(k, off, 16);
            if (v > k) k = v;
        }
        if ((tid & 15) == 0) s_bdi[tid >> 4] = DD - 1 - (int)(k & 0xffffffffu);
    }

    // stage this block's cls rows (coalesced float4; offsets all 16B-aligned)
    const int nrow = min(256, DD - jb * 256);
    const int nvec = nrow * CC / 4;        // integral: nrow*21 % 4 == 0 for 256 and 28
    const float4* src = (const float4*)(cls + ((size_t)b * DD + (size_t)jb * 256) * CC);
    for (int v = tid; v < nvec; v += 256) ((float4*)s_cls)[v] = src[v];
    __syncthreads();

    float sl1 = 0.0f, cepos = 0.0f; int npos = 0;
    if (d < DD) {
        size_t gi = (size_t)b * DD + d;
        float best = bovl[gi];
        int bi = (int)bidx[gi];
        // scatter override, ascending o = last write wins (matches XLA)
        #pragma unroll
        for (int o = 0; o < OO; ++o) {
            if (s_bdi[o] == d) { bi = o; best = 1.0f; }
        }
        int lab = (best < 0.5f) ? 0 : s_lab[bi];

        // CE from LDS row (word stride 21, coprime with 32 banks -> conflict-free)
        float v[CC];
        #pragma unroll
        for (int c = 0; c < CC; ++c) v[c] = s_cls[tid * CC + c];
        float m = v[0];
        #pragma unroll
        for (int c = 1; c < CC; ++c) m = fmaxf(m, v[c]);
        float s = 0.0f;
        #pragma unroll
        for (int c = 0; c < CC; ++c) s += __expf(v[c] - m);   // v_exp_f32
        float xl = v[0];
        #pragma unroll
        for (int c = 1; c < CC; ++c) xl = (lab == c) ? v[c] : xl;  // static idx select
        float ce = m + __logf(s) - xl;                        // v_log_f32

        if (lab > 0) {
            npos = 1; cepos = ce;
            ce_neg[gi] = 0.0f;
            float ax1 = s_ax1[bi], ay1 = s_ay1[bi], ax2 = s_ax2[bi], ay2 = s_ay2[bi];
            float cx = (ax1 + ax2) * 0.5f, cy = (ay1 + ay2) * 0.5f;
            float w = ax2 - ax1, h = ay2 - ay1;
            float4 p = db[d];
            float gx = (cx - p.x) / (p.z / 10.0f);
            float gy = (cy - p.y) / (p.w / 10.0f);
            float gw = __logf(w / p.z) * 5.0f;
            float gh = __logf(h / p.w) * 5.0f;
            float4 lp = loc_pred[gi];
            sl1 = smoothl1(lp.x - gx) + smoothl1(lp.y - gy)
                + smoothl1(lp.z - gw) + smoothl1(lp.w - gh);
        } else {
            ce_neg[gi] = ce;
        }
    }

    #pragma unroll
    for (int off = 32; off; off >>= 1) {
        sl1   += __shfl_xor(sl1, off);
        cepos += __shfl_xor(cepos, off);
        npos  += __shfl_xor(npos, off);
    }
    const int w = tid >> 6;
    if ((tid & 63) == 0) { s_f[w*2+0] = sl1; s_f[w*2+1] = cepos; s_i[w] = npos; }
    __syncthreads();
    if (tid == 0) {
        float sv = 0, cp = 0; int np = 0;
        #pragma unroll
        for (int q = 0; q < 4; ++q) { sv += s_f[q*2+0]; cp += s_f[q*2+1]; np += s_i[q]; }
        const int pi = b * NBLK_D + jb;
        part_sl1[pi] = sv;
        part_ce[pi]  = cp;
        part_np[pi]  = np;
    }
}

// ---------------- topk: sum of top (3*n_pos) negatives, row in registers ---
__global__ __launch_bounds__(256) void topk_kernel(
    const float* __restrict__ ce_neg,
    const int* __restrict__ part_np,       // [B][NBLK_D]
    float* __restrict__ conf_neg_part)     // [B]
{
    const int b = blockIdx.x, tid = threadIdx.x;
    __shared__ int   s_cnt[4];
    __shared__ float s_f[4];

    int np = 0;
    #pragma unroll
    for (int jb = 0; jb < NBLK_D; ++jb) np += part_np[b * NBLK_D + jb];  // uniform
    int k = 3 * np;
    if (k <= 0) { if (tid == 0) conf_neg_part[b] = 0.0f; return; }
    if (k > DD) k = DD;

    float vals[NV];
    #pragma unroll
    for (int q = 0; q < NV; ++q) {
        int d = q * 256 + tid;
        vals[q] = (d < DD) ? ce_neg[(size_t)b * DD + d] : 0.0f;
    }

    unsigned lo = 0u, hi = 0x7f800000u;
    while (hi - lo > 1u) {
        unsigned mid = lo + ((hi - lo) >> 1);
        float t = __uint_as_float(mid);
        int c = 0;
        #pragma unroll
        for (int q = 0; q < NV; ++q) c += (vals[q] >= t) ? 1 : 0;
        #pragma unroll
        for (int off = 32; off; off >>= 1) c += __shfl_xor(c, off);
        if ((tid & 63) == 0) s_cnt[tid >> 6] = c;
        __syncthreads();
        int cnt = s_cnt[0] + s_cnt[1] + s_cnt[2] + s_cnt[3];
        __syncthreads();
        if (cnt >= k) lo = mid; else hi = mid;
    }
    float vk = __uint_as_float(lo);

    float ssum = 0.0f; int cgt = 0;
    #pragma unroll
    for (int q = 0; q < NV; ++q) {
        float v = vals[q];
        if (v > vk) { ssum += v; ++cgt; }
    }
    #pragma unroll
    for (int off = 32; off; off >>= 1) { ssum += __shfl_xor(ssum, off); cgt += __shfl_xor(cgt, off); }
    if ((tid & 63) == 0) { s_f[tid >> 6] = ssum; s_cnt[tid >> 6] = cgt; }
    __syncthreads();
    if (tid == 0) {
        conf_neg_part[b] = s_f[0]+s_f[1]+s_f[2]+s_f[3]
                         + (float)(k - (s_cnt[0]+s_cnt[1]+s_cnt[2]+s_cnt[3])) * vk;
    }
}

// ---------------- final: reduce all partials, emit scalar ------------------
__global__ __launch_bounds__(256) void finalize_kernel(
    const float* __restrict__ part_sl1,       // [NLB]
    const int*   __restrict__ part_np,        // [NLB]
    const float* __restrict__ part_ce,        // [NLB]
    const float* __restrict__ conf_neg_part,  // [B]
    float* __restrict__ out)
{
    const int tid = threadIdx.x;
    float loc = 0.0f, cp = 0.0f; int np = 0;
    for (int i = tid; i < NLB; i += 256) {
        loc += part_sl1[i]; cp += part_ce[i]; np += part_np[i];
    }
    float cn = (tid < BB) ? conf_neg_part[tid] : 0.0f;

    __shared__ float s_f[12];
    __shared__ int s_i[4];
    #pragma unroll
    for (int off = 32; off; off >>= 1) {
        loc += __shfl_xor(loc, off);
        cp  += __shfl_xor(cp, off);
        cn  += __shfl_xor(cn, off);
        np  += __shfl_xor(np, off);
    }
    const int w = tid >> 6;
    if ((tid & 63) == 0) { s_f[w*3+0] = loc; s_f[w*3+1] = cp; s_f[w*3+2] = cn; s_i[w] = np; }
    __syncthreads();
    if (tid == 0) {
        float L = 0, P = 0, N = 0; int T = 0;
        #pragma unroll
        for (int q = 0; q < 4; ++q) { L += s_f[q*3]; P += s_f[q*3+1]; N += s_f[q*3+2]; T += s_i[q]; }
        float npf = (float)T;
        out[0] = L / (npf * 4.0f) + (N + P) / npf;
    }
}

extern "C" void kernel_launch(void* const* d_in, const int* in_sizes, int n_in,
                              void* d_out, int out_size, void* d_ws, size_t ws_size,
                              hipStream_t stream) {
    (void)in_sizes; (void)n_in; (void)out_size; (void)ws_size;
    const float4* loc_pred  = (const float4*)d_in[0];
    const float*  cls_pred  = (const float*)d_in[1];
    const float4* gt_boxes  = (const float4*)d_in[2];
    const int*    gt_labels = (const int*)d_in[3];
    const float4* db        = (const float4*)d_in[4];

    char* ws = (char*)d_ws;
    size_t off = 0;
    auto alloc = [&](size_t bytes) { char* p = ws + off; off = (off + bytes + 15) & ~(size_t)15; return p; };

    unsigned long long* partial = (unsigned long long*)alloc((size_t)BB * OO * CH * 8);
    float* ce_neg        = (float*)alloc((size_t)BB * DD * 4);
    float* bovl          = (float*)alloc((size_t)BB * DD * 4);
    unsigned char* bidx  = (unsigned char*)alloc((size_t)BB * DD);
    float* part_sl1      = (float*)alloc((size_t)NLB * 4);
    int*   part_np       = (int*)alloc((size_t)NLB * 4);
    float* part_ce       = (float*)alloc((size_t)NLB * 4);
    float* conf_neg_part = (float*)alloc((size_t)BB * 4);

    match_a<<<dim3(CH, BB), 256, 0, stream>>>(gt_boxes, db, partial, bovl, bidx);
    fused_main<<<dim3(NBLK_D, BB), 256, 0, stream>>>(loc_pred, cls_pred, gt_boxes,
                                                     gt_labels, db, partial, bovl, bidx,
                                                     ce_neg, part_sl1, part_np, part_ce);
    topk_kernel<<<BB, 256, 0, stream>>>(ce_neg, part_np, conf_neg_part);
    finalize_kernel<<<1, 256, 0, stream>>>(part_sl1, part_np, part_ce, conf_neg_part,
                                           (float*)d_out);
}

// Round 8
// 73.461 us; speedup vs baseline: 3.1045x; 1.0300x over previous
//
#include <hip/hip_runtime.h>

#define BB 128
#define DD 8732
#define OO 16
#define CC 21
#define CH 16        // chunks per image in match phase A
#define CHUNK 546    // ceil(DD/CH)
#define NBLK_D 35    // ceil(DD/256)
#define NLB (BB * NBLK_D)         // fused blocks (= 4480)
#define NV 35        // per-thread register values in topk

__device__ __forceinline__ float smoothl1(float d) {
    float ad = fabsf(d);
    return (ad < 1.0f) ? 0.5f * d * d : ad - 0.5f;
}

// ---- Phase A: per-chunk argmax_d(iou) per gt o  +  per-d best over o ------
// key = (iou_bits << 32) | (DD-1-d)  -> u64 max == max iou, tie -> smallest d
__global__ __launch_bounds__(256) void match_a(
    const float4* __restrict__ gt_boxes,   // [B*O] xyxy
    const float4* __restrict__ db,         // [D] cxcywh
    unsigned long long* __restrict__ partial, // [B][O][CH]
    float* __restrict__ bovl,              // [B*D] best-over-o iou
    unsigned char* __restrict__ bidx,      // [B*D] argmax-over-o (first occurrence)
    int* __restrict__ done_counter)        // zeroed here for topk_final
{
    const int b = blockIdx.y, ch = blockIdx.x, tid = threadIdx.x;
    if (b == 0 && ch == 0 && tid == 0) *done_counter = 0;

    __shared__ float s_ax1[OO], s_ay1[OO], s_ax2[OO], s_ay2[OO], s_area[OO];
    __shared__ unsigned long long s_keys[OO][257];   // padded stride

    if (tid < OO) {
        float4 g = gt_boxes[b * OO + tid];
        s_ax1[tid] = g.x; s_ay1[tid] = g.y; s_ax2[tid] = g.z; s_ay2[tid] = g.w;
        s_area[tid] = (g.z - g.x) * (g.w - g.y);
    }
    __syncthreads();

    unsigned long long key[OO];
    #pragma unroll
    for (int o = 0; o < OO; ++o) key[o] = 0ull;

    const int d0 = ch * CHUNK;
    const int dend = min(d0 + CHUNK, DD);
    for (int d = d0 + tid; d < dend; d += 256) {
        float4 p = db[d];
        float px1 = p.x - p.z * 0.5f, py1 = p.y - p.w * 0.5f;
        float px2 = p.x + p.z * 0.5f, py2 = p.y + p.w * 0.5f;
        float area_b = (px2 - px1) * (py2 - py1);
        unsigned dl = (unsigned)(DD - 1 - d);
        float best = -1.0f; int bi = 0;
        #pragma unroll
        for (int o = 0; o < OO; ++o) {
            float w = fmaxf(fminf(s_ax2[o], px2) - fmaxf(s_ax1[o], px1), 0.0f);
            float h = fmaxf(fminf(s_ay2[o], py2) - fmaxf(s_ay1[o], py1), 0.0f);
            float inter = w * h;
            float iou = inter / (s_area[o] + area_b - inter);
            unsigned long long kk = ((unsigned long long)__float_as_uint(iou) << 32) | dl;
            if (kk > key[o]) key[o] = kk;
            if (iou > best) { best = iou; bi = o; }   // first occurrence over o
        }
        bovl[(size_t)b * DD + d] = best;
        bidx[(size_t)b * DD + d] = (unsigned char)bi;
    }
    #pragma unroll
    for (int o = 0; o < OO; ++o) s_keys[o][tid] = key[o];
    __syncthreads();

    // transpose reduce: thread t -> o = t>>4, j = t&15; 16 strided reads + shfl
    const int o = tid >> 4, j = tid & 15;
    unsigned long long mx = s_keys[o][j];
    #pragma unroll
    for (int m = 1; m < 16; ++m) {
        unsigned long long v = s_keys[o][j + 16 * m];
        if (v > mx) mx = v;
    }
    #pragma unroll
    for (int off = 8; off; off >>= 1) {
        unsigned long long v = __shfl_xor(mx, off, 16);
        if (v > mx) mx = v;
    }
    if (j == 0) partial[((size_t)b * OO + o) * CH + ch] = mx;
}

// ---- fused: bdi-reduce + label + encode/SL1 + CE (LDS-staged cls) ---------
__global__ __launch_bounds__(256) void fused_main(
    const float4* __restrict__ loc_pred,   // [B*D]
    const float*  __restrict__ cls,        // [B*D*C]
    const float4* __restrict__ gt_boxes,   // [B*O]
    const int*    __restrict__ gt_labels,  // [B*O]
    const float4* __restrict__ db,         // [D]
    const unsigned long long* __restrict__ partial, // [B][O][CH]
    const float* __restrict__ bovl,        // [B*D]
    const unsigned char* __restrict__ bidx,// [B*D]
    float* __restrict__ ce_neg,            // [B*D]
    float* __restrict__ part_sl1,          // [NLB] layout [b][jb]
    int*   __restrict__ part_np,           // [NLB]
    float* __restrict__ part_ce)           // [NLB]
{
    const int b = blockIdx.y, jb = blockIdx.x, tid = threadIdx.x;
    const int d = jb * 256 + tid;
    __shared__ float s_cls[256 * CC];      // 21504 B
    __shared__ float s_ax1[OO], s_ay1[OO], s_ax2[OO], s_ay2[OO];
    __shared__ int   s_lab[OO], s_bdi[OO];
    __shared__ float s_f[8];
    __shared__ int   s_i[4];

    if (tid < OO) {
        float4 g = gt_boxes[b * OO + tid];
        s_ax1[tid] = g.x; s_ay1[tid] = g.y; s_ax2[tid] = g.z; s_ay2[tid] = g.w;
        s_lab[tid] = gt_labels[b * OO + tid];
    }

    // in-block match_b: 256 threads load 16x16 chunk partials, reduce per group of 16
    {
        unsigned long long k = partial[(size_t)b * (OO * CH) + tid]; // o=tid>>4, ch=tid&15
        #pragma unroll
        for (int off = 8; off; off >>= 1) {
            unsigned long long v = __shfl_xor(k, off, 16);
            if (v > k) k = v;
        }
        if ((tid & 15) == 0) s_bdi[tid >> 4] = DD - 1 - (int)(k & 0xffffffffu);
    }

    // stage this block's cls rows (coalesced float4; offsets all 16B-aligned)
    const int nrow = min(256, DD - jb * 256);
    const int nvec = nrow * CC / 4;        // integral: nrow*21 % 4 == 0 for 256 and 28
    const float4* src = (const float4*)(cls + ((size_t)b * DD + (size_t)jb * 256) * CC);
    for (int v = tid; v < nvec; v += 256) ((float4*)s_cls)[v] = src[v];
    __syncthreads();

    float sl1 = 0.0f, cepos = 0.0f; int npos = 0;
    if (d < DD) {
        size_t gi = (size_t)b * DD + d;
        float best = bovl[gi];
        int bi = (int)bidx[gi];
        // scatter override, ascending o = last write wins (matches XLA)
        #pragma unroll
        for (int o = 0; o < OO; ++o) {
            if (s_bdi[o] == d) { bi = o; best = 1.0f; }
        }
        int lab = (best < 0.5f) ? 0 : s_lab[bi];

        // CE from LDS row (word stride 21, coprime with 32 banks -> conflict-free)
        float v[CC];
        #pragma unroll
        for (int c = 0; c < CC; ++c) v[c] = s_cls[tid * CC + c];
        float m = v[0];
        #pragma unroll
        for (int c = 1; c < CC; ++c) m = fmaxf(m, v[c]);
        float s = 0.0f;
        #pragma unroll
        for (int c = 0; c < CC; ++c) s += __expf(v[c] - m);   // v_exp_f32
        float xl = v[0];
        #pragma unroll
        for (int c = 1; c < CC; ++c) xl = (lab == c) ? v[c] : xl;  // static idx select
        float ce = m + __logf(s) - xl;                        // v_log_f32

        if (lab > 0) {
            npos = 1; cepos = ce;
            ce_neg[gi] = 0.0f;
            float ax1 = s_ax1[bi], ay1 = s_ay1[bi], ax2 = s_ax2[bi], ay2 = s_ay2[bi];
            float cx = (ax1 + ax2) * 0.5f, cy = (ay1 + ay2) * 0.5f;
            float w = ax2 - ax1, h = ay2 - ay1;
            float4 p = db[d];
            float gx = (cx - p.x) / (p.z / 10.0f);
            float gy = (cy - p.y) / (p.w / 10.0f);
            float gw = __logf(w / p.z) * 5.0f;
            float gh = __logf(h / p.w) * 5.0f;
            float4 lp = loc_pred[gi];
            sl1 = smoothl1(lp.x - gx) + smoothl1(lp.y - gy)
                + smoothl1(lp.z - gw) + smoothl1(lp.w - gh);
        } else {
            ce_neg[gi] = ce;
        }
    }

    #pragma unroll
    for (int off = 32; off; off >>= 1) {
        sl1   += __shfl_xor(sl1, off);
        cepos += __shfl_xor(cepos, off);
        npos  += __shfl_xor(npos, off);
    }
    const int w = tid >> 6;
    if ((tid & 63) == 0) { s_f[w*2+0] = sl1; s_f[w*2+1] = cepos; s_i[w] = npos; }
    __syncthreads();
    if (tid == 0) {
        float sv = 0, cp = 0; int np = 0;
        #pragma unroll
        for (int q = 0; q < 4; ++q) { sv += s_f[q*2+0]; cp += s_f[q*2+1]; np += s_i[q]; }
        const int pi = b * NBLK_D + jb;
        part_sl1[pi] = sv;
        part_ce[pi]  = cp;
        part_np[pi]  = np;
    }
}

// ---- topk via 4-pass radix select + last-block finalize -------------------
// order-preserving key: k = u ^ (u<0 ? 0xFFFFFFFF : 0x80000000); larger f -> larger k
__global__ __launch_bounds__(256) void topk_final(
    const float* __restrict__ ce_neg,
    const int*   __restrict__ part_np,        // [B][NBLK_D]
    const float* __restrict__ part_sl1,       // [NLB]
    const float* __restrict__ part_ce,        // [NLB]
    float* __restrict__ conf_neg_part,        // [B]
    int*   __restrict__ done_counter,
    float* __restrict__ out)
{
    const int b = blockIdx.x, tid = threadIdx.x;
    __shared__ int      hist[256];
    __shared__ unsigned s_pk[2];
    __shared__ float    s_f[12];
    __shared__ int      s_c[4];
    __shared__ int      s_last;

    int np = 0;
    #pragma unroll
    for (int jb = 0; jb < NBLK_D; ++jb) np += part_np[b * NBLK_D + jb];  // uniform
    int k0 = 3 * np;
    if (k0 > DD) k0 = DD;

    float row = 0.0f;
    if (k0 > 0) {    // uniform per block
        unsigned kx[NV];
        #pragma unroll
        for (int q = 0; q < NV; ++q) {
            int d = q * 256 + tid;
            float v = (d < DD) ? ce_neg[(size_t)b * DD + d] : 0.0f;  // pads are harmless zeros
            unsigned u = __float_as_uint(v);
            kx[q] = u ^ ((unsigned)((int)u >> 31) | 0x80000000u);
        }

        unsigned prefix = 0u; int k = k0;
        #pragma unroll
        for (int p = 0; p < 4; ++p) {
            const int shift = 24 - 8 * p;
            hist[tid] = 0;
            __syncthreads();
            #pragma unroll
            for (int q = 0; q < NV; ++q) {
                if (p == 0 || ((kx[q] ^ prefix) >> (shift + 8)) == 0u)
                    atomicAdd(&hist[(kx[q] >> shift) & 255], 1);
            }
            __syncthreads();
            if (tid < 64) {   // wave 0: descending suffix scan, 4 bins/lane
                int h0 = hist[255 - 4*tid], h1 = hist[254 - 4*tid],
                    h2 = hist[253 - 4*tid], h3 = hist[252 - 4*tid];
                int sl = h0 + h1 + h2 + h3;
                int run = sl;
                #pragma unroll
                for (int off = 1; off < 64; off <<= 1) {
                    int v = __shfl_up(run, off);
                    if (tid >= off) run += v;
                }
                int pre = run - sl;           // count in bins strictly higher
                if (pre < k && k <= pre + sl) {   // exactly one lane
                    int hh[4] = {h0, h1, h2, h3};
                    int c = pre, byte = -1, knew = 0;
                    #pragma unroll
                    for (int j = 0; j < 4; ++j) {
                        if (byte < 0 && c + hh[j] >= k) { byte = 255 - 4*tid - j; knew = k - c; }
                        c += hh[j];
                    }
                    s_pk[0] = prefix | ((unsigned)byte << shift);
                    s_pk[1] = (unsigned)knew;
                }
            }
            __syncthreads();
            prefix = s_pk[0]; k = (int)s_pk[1];
            // safe: s_pk next written only after 2 more syncs
        }

        unsigned vb = (prefix & 0x80000000u) ? (prefix ^ 0x80000000u) : ~prefix;
        float vk = __uint_as_float(vb);        // exact k-th largest value

        float ssum = 0.0f; int cgt = 0;
        #pragma unroll
        for (int q = 0; q < NV; ++q) {
            if (kx[q] > prefix) {
                unsigned u = (kx[q] & 0x80000000u) ? (kx[q] ^ 0x80000000u) : ~kx[q];
                ssum += __uint_as_float(u);
                ++cgt;
            }
        }
        #pragma unroll
        for (int off = 32; off; off >>= 1) { ssum += __shfl_xor(ssum, off); cgt += __shfl_xor(cgt, off); }
        if ((tid & 63) == 0) { s_f[tid >> 6] = ssum; s_c[tid >> 6] = cgt; }
        __syncthreads();
        row = s_f[0]+s_f[1]+s_f[2]+s_f[3]
            + (float)(k0 - (s_c[0]+s_c[1]+s_c[2]+s_c[3])) * vk;   // exact tie handling
    }

    if (tid == 0) {
        conf_neg_part[b] = row;
        __threadfence();
        int prev = atomicAdd(done_counter, 1);
        s_last = (prev == BB - 1) ? 1 : 0;
    }
    __syncthreads();
    if (s_last) {                                // one block; fixed-order reduce -> deterministic
        __threadfence();
        float loc = 0.0f, cp = 0.0f; int npt = 0;
        for (int i = tid; i < NLB; i += 256) {
            loc += part_sl1[i]; cp += part_ce[i]; npt += part_np[i];
        }
        float cn = (tid < BB) ? conf_neg_part[tid] : 0.0f;
        #pragma unroll
        for (int off = 32; off; off >>= 1) {
            loc += __shfl_xor(loc, off);
            cp  += __shfl_xor(cp, off);
            cn  += __shfl_xor(cn, off);
            npt += __shfl_xor(npt, off);
        }
        const int w = tid >> 6;
        if ((tid & 63) == 0) { s_f[w*3+0] = loc; s_f[w*3+1] = cp; s_f[w*3+2] = cn; s_c[w] = npt; }
        __syncthreads();
        if (tid == 0) {
            float L = 0, P = 0, N = 0; int T = 0;
            #pragma unroll
            for (int q = 0; q < 4; ++q) { L += s_f[q*3]; P += s_f[q*3+1]; N += s_f[q*3+2]; T += s_c[q]; }
            float npf = (float)T;
            out[0] = L / (npf * 4.0f) + (N + P) / npf;
        }
    }
}

extern "C" void kernel_launch(void* const* d_in, const int* in_sizes, int n_in,
                              void* d_out, int out_size, void* d_ws, size_t ws_size,
                              hipStream_t stream) {
    (void)in_sizes; (void)n_in; (void)out_size; (void)ws_size;
    const float4* loc_pred  = (const float4*)d_in[0];
    const float*  cls_pred  = (const float*)d_in[1];
    const float4* gt_boxes  = (const float4*)d_in[2];
    const int*    gt_labels = (const int*)d_in[3];
    const float4* db        = (const float4*)d_in[4];

    char* ws = (char*)d_ws;
    size_t off = 0;
    auto alloc = [&](size_t bytes) { char* p = ws + off; off = (off + bytes + 15) & ~(size_t)15; return p; };

    unsigned long long* partial = (unsigned long long*)alloc((size_t)BB * OO * CH * 8);
    float* ce_neg        = (float*)alloc((size_t)BB * DD * 4);
    float* bovl          = (float*)alloc((size_t)BB * DD * 4);
    unsigned char* bidx  = (unsigned char*)alloc((size_t)BB * DD);
    float* part_sl1      = (float*)alloc((size_t)NLB * 4);
    int*   part_np       = (int*)alloc((size_t)NLB * 4);
    float* part_ce       = (float*)alloc((size_t)NLB * 4);
    float* conf_neg_part = (float*)alloc((size_t)BB * 4);
    int*   done_counter  = (int*)alloc(sizeof(int));

    match_a<<<dim3(CH, BB), 256, 0, stream>>>(gt_boxes, db, partial, bovl, bidx,
                                              done_counter);
    fused_main<<<dim3(NBLK_D, BB), 256, 0, stream>>>(loc_pred, cls_pred, gt_boxes,
                                                     gt_labels, db, partial, bovl, bidx,
                                                     ce_neg, part_sl1, part_np, part_ce);
    topk_final<<<BB, 256, 0, stream>>>(ce_neg, part_np, part_sl1, part_ce,
                                       conf_neg_part, done_counter, (float*)d_out);
}

// Round 9
// 72.311 us; speedup vs baseline: 3.1538x; 1.0159x over previous
//
#include <hip/hip_runtime.h>

#define BB 128
#define DD 8732
#define OO 16
#define CC 21
#define CH 16        // chunks per image in match phase A
#define CHUNK 546    // ceil(DD/CH)
#define NBLK_D 35    // ceil(DD/256)
#define NLB (BB * NBLK_D)         // fused blocks (= 4480)
#define NV 35        // per-thread register values in topk

typedef __attribute__((address_space(3))) unsigned int lds_u32;
typedef const __attribute__((address_space(1))) unsigned int glb_u32;

__device__ __forceinline__ float smoothl1(float d) {
    float ad = fabsf(d);
    return (ad < 1.0f) ? 0.5f * d * d : ad - 0.5f;
}

// ---- Phase A: per-chunk argmax_d(iou) per gt o  +  per-d best over o ------
// key = (iou_bits << 32) | (DD-1-d)  -> u64 max == max iou, tie -> smallest d
__global__ __launch_bounds__(256) void match_a(
    const float4* __restrict__ gt_boxes,   // [B*O] xyxy
    const float4* __restrict__ db,         // [D] cxcywh
    unsigned long long* __restrict__ partial, // [B][O][CH]
    float* __restrict__ bovl,              // [B*D] best-over-o iou
    unsigned char* __restrict__ bidx,      // [B*D] argmax-over-o (first occurrence)
    int* __restrict__ done_counter)        // zeroed here for topk_final
{
    const int b = blockIdx.y, ch = blockIdx.x, tid = threadIdx.x;
    if (b == 0 && ch == 0 && tid == 0) *done_counter = 0;

    __shared__ float s_ax1[OO], s_ay1[OO], s_ax2[OO], s_ay2[OO], s_area[OO];
    __shared__ unsigned long long s_keys[OO][257];   // padded stride

    if (tid < OO) {
        float4 g = gt_boxes[b * OO + tid];
        s_ax1[tid] = g.x; s_ay1[tid] = g.y; s_ax2[tid] = g.z; s_ay2[tid] = g.w;
        s_area[tid] = (g.z - g.x) * (g.w - g.y);
    }
    __syncthreads();

    unsigned long long key[OO];
    #pragma unroll
    for (int o = 0; o < OO; ++o) key[o] = 0ull;

    const int d0 = ch * CHUNK;
    const int dend = min(d0 + CHUNK, DD);
    for (int d = d0 + tid; d < dend; d += 256) {
        float4 p = db[d];
        float px1 = p.x - p.z * 0.5f, py1 = p.y - p.w * 0.5f;
        float px2 = p.x + p.z * 0.5f, py2 = p.y + p.w * 0.5f;
        float area_b = (px2 - px1) * (py2 - py1);
        unsigned dl = (unsigned)(DD - 1 - d);
        float best = -1.0f; int bi = 0;
        #pragma unroll
        for (int o = 0; o < OO; ++o) {
            float w = fmaxf(fminf(s_ax2[o], px2) - fmaxf(s_ax1[o], px1), 0.0f);
            float h = fmaxf(fminf(s_ay2[o], py2) - fmaxf(s_ay1[o], py1), 0.0f);
            float inter = w * h;
            float iou = inter / (s_area[o] + area_b - inter);
            unsigned long long kk = ((unsigned long long)__float_as_uint(iou) << 32) | dl;
            if (kk > key[o]) key[o] = kk;
            if (iou > best) { best = iou; bi = o; }   // first occurrence over o
        }
        bovl[(size_t)b * DD + d] = best;
        bidx[(size_t)b * DD + d] = (unsigned char)bi;
    }
    #pragma unroll
    for (int o = 0; o < OO; ++o) s_keys[o][tid] = key[o];
    __syncthreads();

    // transpose reduce: thread t -> o = t>>4, j = t&15; 16 strided reads + shfl
    const int o = tid >> 4, j = tid & 15;
    unsigned long long mx = s_keys[o][j];
    #pragma unroll
    for (int m = 1; m < 16; ++m) {
        unsigned long long v = s_keys[o][j + 16 * m];
        if (v > mx) mx = v;
    }
    #pragma unroll
    for (int off = 8; off; off >>= 1) {
        unsigned long long v = __shfl_xor(mx, off, 16);
        if (v > mx) mx = v;
    }
    if (j == 0) partial[((size_t)b * OO + o) * CH + ch] = mx;
}

// ---- fused v2: async LDS staging + bdi-reduce + label + SL1 + CE ----------
__global__ __launch_bounds__(256) void fused_main(
    const float4* __restrict__ loc_pred,   // [B*D]
    const float*  __restrict__ cls,        // [B*D*C]
    const float4* __restrict__ gt_boxes,   // [B*O]
    const int*    __restrict__ gt_labels,  // [B*O]
    const float4* __restrict__ db,         // [D]
    const unsigned long long* __restrict__ partial, // [B][O][CH]
    const float* __restrict__ bovl,        // [B*D]
    const unsigned char* __restrict__ bidx,// [B*D]
    float* __restrict__ ce_neg,            // [B*D]
    float* __restrict__ part_sl1,          // [NLB] layout [b][jb]
    int*   __restrict__ part_np,           // [NLB]
    float* __restrict__ part_ce)           // [NLB]
{
    const int b = blockIdx.y, jb = blockIdx.x, tid = threadIdx.x;
    const int d = jb * 256 + tid;
    __shared__ float s_cls[256 * CC];      // 21504 B
    __shared__ float s_ax1[OO], s_ay1[OO], s_ax2[OO], s_ay2[OO];
    __shared__ int   s_lab[OO], s_bdi[OO];
    __shared__ float s_f[8];
    __shared__ int   s_i[4];

    // ---- issue async global->LDS staging FIRST (16B/lane/issue, linear dest)
    const int nrow = min(256, DD - jb * 256);
    const int nvec = nrow * CC / 4;        // 1344 for full blocks, 147 for tail
    const float4* src = (const float4*)(cls + ((size_t)b * DD + (size_t)jb * 256) * CC);
    if (nvec == 1344) {
        #pragma unroll
        for (int c = 0; c < 5; ++c) {
            int v = c * 256 + tid;
            __builtin_amdgcn_global_load_lds((glb_u32*)(src + v),
                                             (lds_u32*)&s_cls[v * 4], 16, 0, 0);
        }
        if (tid < 64) {
            int v = 5 * 256 + tid;
            __builtin_amdgcn_global_load_lds((glb_u32*)(src + v),
                                             (lds_u32*)&s_cls[v * 4], 16, 0, 0);
        }
    } else {
        for (int v = tid; v < nvec; v += 256)
            __builtin_amdgcn_global_load_lds((glb_u32*)(src + v),
                                             (lds_u32*)&s_cls[v * 4], 16, 0, 0);
    }

    // ---- cls-independent work while staging is in flight
    if (tid < OO) {
        float4 g = gt_boxes[b * OO + tid];
        s_ax1[tid] = g.x; s_ay1[tid] = g.y; s_ax2[tid] = g.z; s_ay2[tid] = g.w;
        s_lab[tid] = gt_labels[b * OO + tid];
    }
    {   // in-block match_b: 16x16 chunk partials -> s_bdi
        unsigned long long k = partial[(size_t)b * (OO * CH) + tid]; // o=tid>>4, ch=tid&15
        #pragma unroll
        for (int off = 8; off; off >>= 1) {
            unsigned long long v = __shfl_xor(k, off, 16);
            if (v > k) k = v;
        }
        if ((tid & 15) == 0) s_bdi[tid >> 4] = DD - 1 - (int)(k & 0xffffffffu);
    }
    const size_t gi = (size_t)b * DD + d;
    float best = 0.0f; int bi = 0;
    if (d < DD) { best = bovl[gi]; bi = (int)bidx[gi]; }   // in flight across barrier

    __syncthreads();   // drains staging (vmcnt) + LDS writes

    float sl1 = 0.0f, cepos = 0.0f; int npos = 0;
    if (d < DD) {
        // scatter override, ascending o = last write wins (matches XLA)
        #pragma unroll
        for (int o = 0; o < OO; ++o) {
            if (s_bdi[o] == d) { bi = o; best = 1.0f; }
        }
        int lab = (best < 0.5f) ? 0 : s_lab[bi];

        // CE from LDS row (word stride 21, coprime with 32 banks -> conflict-free)
        float v[CC];
        #pragma unroll
        for (int c = 0; c < CC; ++c) v[c] = s_cls[tid * CC + c];
        float m = v[0];
        #pragma unroll
        for (int c = 1; c < CC; ++c) m = fmaxf(m, v[c]);
        float s = 0.0f;
        #pragma unroll
        for (int c = 0; c < CC; ++c) s += __expf(v[c] - m);   // v_exp_f32
        float xl = s_cls[tid * CC + lab];                     // one runtime-offset read
        float ce = m + __logf(s) - xl;                        // v_log_f32

        if (lab > 0) {
            npos = 1; cepos = ce;
            float ax1 = s_ax1[bi], ay1 = s_ay1[bi], ax2 = s_ax2[bi], ay2 = s_ay2[bi];
            float cx = (ax1 + ax2) * 0.5f, cy = (ay1 + ay2) * 0.5f;
            float w = ax2 - ax1, h = ay2 - ay1;
            float4 p = db[d];
            float gx = (cx - p.x) / (p.z / 10.0f);
            float gy = (cy - p.y) / (p.w / 10.0f);
            float gw = __logf(w / p.z) * 5.0f;
            float gh = __logf(h / p.w) * 5.0f;
            float4 lp = loc_pred[gi];
            sl1 = smoothl1(lp.x - gx) + smoothl1(lp.y - gy)
                + smoothl1(lp.z - gw) + smoothl1(lp.w - gh);
        }
        ce_neg[gi] = (lab > 0) ? 0.0f : ce;
    }

    #pragma unroll
    for (int off = 32; off; off >>= 1) {
        sl1   += __shfl_xor(sl1, off);
        cepos += __shfl_xor(cepos, off);
        npos  += __shfl_xor(npos, off);
    }
    const int w = tid >> 6;
    if ((tid & 63) == 0) { s_f[w*2+0] = sl1; s_f[w*2+1] = cepos; s_i[w] = npos; }
    __syncthreads();
    if (tid == 0) {
        float sv = 0, cp = 0; int np = 0;
        #pragma unroll
        for (int q = 0; q < 4; ++q) { sv += s_f[q*2+0]; cp += s_f[q*2+1]; np += s_i[q]; }
        const int pi = b * NBLK_D + jb;
        part_sl1[pi] = sv;
        part_ce[pi]  = cp;
        part_np[pi]  = np;
    }
}

// ---- topk via 4-pass radix select + last-block finalize -------------------
// order-preserving key: k = u ^ (u<0 ? 0xFFFFFFFF : 0x80000000); larger f -> larger k
__global__ __launch_bounds__(256) void topk_final(
    const float* __restrict__ ce_neg,
    const int*   __restrict__ part_np,        // [B][NBLK_D]
    const float* __restrict__ part_sl1,       // [NLB]
    const float* __restrict__ part_ce,        // [NLB]
    float* __restrict__ conf_neg_part,        // [B]
    int*   __restrict__ done_counter,
    float* __restrict__ out)
{
    const int b = blockIdx.x, tid = threadIdx.x;
    __shared__ int      hist[256];
    __shared__ unsigned s_pk[2];
    __shared__ float    s_f[12];
    __shared__ int      s_c[4];
    __shared__ int      s_last;

    int np = 0;
    #pragma unroll
    for (int jb = 0; jb < NBLK_D; ++jb) np += part_np[b * NBLK_D + jb];  // uniform
    int k0 = 3 * np;
    if (k0 > DD) k0 = DD;

    float row = 0.0f;
    if (k0 > 0) {    // uniform per block
        unsigned kx[NV];
        #pragma unroll
        for (int q = 0; q < NV; ++q) {
            int d = q * 256 + tid;
            float v = (d < DD) ? ce_neg[(size_t)b * DD + d] : 0.0f;  // pads are harmless zeros
            unsigned u = __float_as_uint(v);
            kx[q] = u ^ ((unsigned)((int)u >> 31) | 0x80000000u);
        }

        unsigned prefix = 0u; int k = k0;
        #pragma unroll
        for (int p = 0; p < 4; ++p) {
            const int shift = 24 - 8 * p;
            hist[tid] = 0;
            __syncthreads();
            #pragma unroll
            for (int q = 0; q < NV; ++q) {
                if (p == 0 || ((kx[q] ^ prefix) >> (shift + 8)) == 0u)
                    atomicAdd(&hist[(kx[q] >> shift) & 255], 1);
            }
            __syncthreads();
            if (tid < 64) {   // wave 0: descending suffix scan, 4 bins/lane
                int h0 = hist[255 - 4*tid], h1 = hist[254 - 4*tid],
                    h2 = hist[253 - 4*tid], h3 = hist[252 - 4*tid];
                int sl = h0 + h1 + h2 + h3;
                int run = sl;
                #pragma unroll
                for (int off = 1; off < 64; off <<= 1) {
                    int v = __shfl_up(run, off);
                    if (tid >= off) run += v;
                }
                int pre = run - sl;           // count in bins strictly higher
                if (pre < k && k <= pre + sl) {   // exactly one lane
                    int hh[4] = {h0, h1, h2, h3};
                    int c = pre, byte = -1, knew = 0;
                    #pragma unroll
                    for (int j = 0; j < 4; ++j) {
                        if (byte < 0 && c + hh[j] >= k) { byte = 255 - 4*tid - j; knew = k - c; }
                        c += hh[j];
                    }
                    s_pk[0] = prefix | ((unsigned)byte << shift);
                    s_pk[1] = (unsigned)knew;
                }
            }
            __syncthreads();
            prefix = s_pk[0]; k = (int)s_pk[1];
            // safe: s_pk next written only after 2 more syncs
        }

        unsigned vb = (prefix & 0x80000000u) ? (prefix ^ 0x80000000u) : ~prefix;
        float vk = __uint_as_float(vb);        // exact k-th largest value

        float ssum = 0.0f; int cgt = 0;
        #pragma unroll
        for (int q = 0; q < NV; ++q) {
            if (kx[q] > prefix) {
                unsigned u = (kx[q] & 0x80000000u) ? (kx[q] ^ 0x80000000u) : ~kx[q];
                ssum += __uint_as_float(u);
                ++cgt;
            }
        }
        #pragma unroll
        for (int off = 32; off; off >>= 1) { ssum += __shfl_xor(ssum, off); cgt += __shfl_xor(cgt, off); }
        if ((tid & 63) == 0) { s_f[tid >> 6] = ssum; s_c[tid >> 6] = cgt; }
        __syncthreads();
        row = s_f[0]+s_f[1]+s_f[2]+s_f[3]
            + (float)(k0 - (s_c[0]+s_c[1]+s_c[2]+s_c[3])) * vk;   // exact tie handling
    }

    if (tid == 0) {
        conf_neg_part[b] = row;
        __threadfence();
        int prev = atomicAdd(done_counter, 1);
        s_last = (prev == BB - 1) ? 1 : 0;
    }
    __syncthreads();
    if (s_last) {                                // one block; fixed-order reduce -> deterministic
        __threadfence();
        float loc = 0.0f, cp = 0.0f; int npt = 0;
        for (int i = tid; i < NLB; i += 256) {
            loc += part_sl1[i]; cp += part_ce[i]; npt += part_np[i];
        }
        float cn = (tid < BB) ? conf_neg_part[tid] : 0.0f;
        #pragma unroll
        for (int off = 32; off; off >>= 1) {
            loc += __shfl_xor(loc, off);
            cp  += __shfl_xor(cp, off);
            cn  += __shfl_xor(cn, off);
            npt += __shfl_xor(npt, off);
        }
        const int w = tid >> 6;
        if ((tid & 63) == 0) { s_f[w*3+0] = loc; s_f[w*3+1] = cp; s_f[w*3+2] = cn; s_c[w] = npt; }
        __syncthreads();
        if (tid == 0) {
            float L = 0, P = 0, N = 0; int T = 0;
            #pragma unroll
            for (int q = 0; q < 4; ++q) { L += s_f[q*3]; P += s_f[q*3+1]; N += s_f[q*3+2]; T += s_c[q]; }
            float npf = (float)T;
            out[0] = L / (npf * 4.0f) + (N + P) / npf;
        }
    }
}

extern "C" void kernel_launch(void* const* d_in, const int* in_sizes, int n_in,
                              void* d_out, int out_size, void* d_ws, size_t ws_size,
                              hipStream_t stream) {
    (void)in_sizes; (void)n_in; (void)out_size; (void)ws_size;
    const float4* loc_pred  = (const float4*)d_in[0];
    const float*  cls_pred  = (const float*)d_in[1];
    const float4* gt_boxes  = (const float4*)d_in[2];
    const int*    gt_labels = (const int*)d_in[3];
    const float4* db        = (const float4*)d_in[4];

    char* ws = (char*)d_ws;
    size_t off = 0;
    auto alloc = [&](size_t bytes) { char* p = ws + off; off = (off + bytes + 15) & ~(size_t)15; return p; };

    unsigned long long* partial = (unsigned long long*)alloc((size_t)BB * OO * CH * 8);
    float* ce_neg        = (float*)alloc((size_t)BB * DD * 4);
    float* bovl          = (float*)alloc((size_t)BB * DD * 4);
    unsigned char* bidx  = (unsigned char*)alloc((size_t)BB * DD);
    float* part_sl1      = (float*)alloc((size_t)NLB * 4);
    int*   part_np       = (int*)alloc((size_t)NLB * 4);
    float* part_ce       = (float*)alloc((size_t)NLB * 4);
    float* conf_neg_part = (float*)alloc((size_t)BB * 4);
    int*   done_counter  = (int*)alloc(sizeof(int));

    match_a<<<dim3(CH, BB), 256, 0, stream>>>(gt_boxes, db, partial, bovl, bidx,
                                              done_counter);
    fused_main<<<dim3(NBLK_D, BB), 256, 0, stream>>>(loc_pred, cls_pred, gt_boxes,
                                                     gt_labels, db, partial, bovl, bidx,
                                                     ce_neg, part_sl1, part_np, part_ce);
    topk_final<<<BB, 256, 0, stream>>>(ce_neg, part_np, part_sl1, part_ce,
                                       conf_neg_part, done_counter, (float*)d_out);
}